// Round 6
// baseline (138.419 us; speedup 1.0000x reference)
//
#include <hip/hip_runtime.h>
#include <hip/hip_bf16.h>

// MsPAM+CAM fused, MI355X gfx950.  B=2, C=64, H=W=64, N=4096, Cq=8.
// 4-kernel pipeline. Softmax normalization folded into MFMA via spare Q/K
// slots (Q 8..13 = -log2(S) split pair, K one-hot 1.0), patched per-block.
// PAM pass2 keeps P entirely in registers via a k-permutation sigma applied
// to both the PV B-frag assembly (cvt_pk + shfl_xor 32) and V's layout (Vp).

typedef __attribute__((ext_vector_type(8))) short bf16x8;
typedef __attribute__((ext_vector_type(4))) short s16x4;
typedef __attribute__((ext_vector_type(4))) float f32x4;

#define MFMA16(a, b, c) __builtin_amdgcn_mfma_f32_16x16x32_bf16(a, b, c, 0, 0, 0)
#define EX2(x) __builtin_amdgcn_exp2f(x)
#define LOG2E 1.4426950408889634f

__device__ __forceinline__ float bf2f(ushort u) {
  union { unsigned int i; float f; } v; v.i = ((unsigned int)u) << 16; return v.f;
}
__device__ __forceinline__ ushort f2bf(float f) {  // RNE
  union { float f; unsigned int i; } v; v.f = f;
  unsigned int r = v.i + 0x7FFFu + ((v.i >> 16) & 1u);
  return (ushort)(r >> 16);
}
__device__ __forceinline__ float loadf(const void* p, size_t i, int isbf) {
  return isbf ? bf2f(((const ushort*)p)[i]) : ((const float*)p)[i];
}
__device__ __forceinline__ bf16x8 load8(const void* p, size_t i, int isbf) {
  if (isbf) return *(const bf16x8*)((const ushort*)p + i);
  const float* f = (const float*)p + i;
  bf16x8 r;
#pragma unroll
  for (int j = 0; j < 8; ++j) r[j] = (short)f2bf(f[j]);
  return r;
}
__device__ __forceinline__ void loadf8(const void* p, size_t i, int isbf, float* o) {
  if (isbf) {
    bf16x8 v = *(const bf16x8*)((const ushort*)p + i);
#pragma unroll
    for (int j = 0; j < 8; ++j) o[j] = bf2f((ushort)v[j]);
  } else {
    const float* f = (const float*)p + i;
#pragma unroll
    for (int j = 0; j < 8; ++j) o[j] = f[j];
  }
}
// per-block dtype detect: bf16-packed x has low-16 exponent bits in [120,133].
__device__ __forceinline__ int detect_isbf(const unsigned int* xw, int* sflag) {
  int t = threadIdx.x;
  if (t < 64) {
    unsigned int w1 = xw[t], w2 = xw[64 + t];
    unsigned int e1 = (w1 >> 7) & 0xFFu, e2 = (w2 >> 7) & 0xFFu;
    unsigned long long b1 = __ballot(e1 >= 120u && e1 <= 133u);
    unsigned long long b2 = __ballot(e2 >= 120u && e2 <= 133u);
    if (t == 0) *sflag = (__popcll(b1) + __popcll(b2) > 64) ? 1 : 0;
  }
  __syncthreads();
  return *sflag;
}

// ---------------------------------------------------------------------------
// KA: fused prep. blocks 0..127: Q/K convs -> QT/KT; 128..383: Vp (sigma-
//     permuted V conv); 384..479: CAM gram partials e_part.
__global__ __launch_bounds__(256) void k_prep_all(
    const void* __restrict__ x, const void* __restrict__ y, const void* __restrict__ z,
    const void* __restrict__ wq, const void* __restrict__ bq,
    const void* __restrict__ wk1, const void* __restrict__ bk1,
    const void* __restrict__ wk2, const void* __restrict__ bk2,
    const void* __restrict__ wk3, const void* __restrict__ bk3,
    const void* __restrict__ wv, const void* __restrict__ bv,
    ushort* __restrict__ QT, ushort* __restrict__ KT, ushort* __restrict__ Vp,
    float* __restrict__ e_part)
{
  __shared__ float wsh[4][8][64];
  __shared__ int sflag;
  int isbf = detect_isbf((const unsigned int*)x, &sflag);
  int blk = blockIdx.x, t = threadIdx.x;

  if (blk < 128) {
    // ---- Q/K1/K2/K3 convs, 4 threads per n (16 c each) + quad shfl reduce
    for (int i = t; i < 2048; i += 256) {
      int mat = i >> 9, rem = i & 511;
      const void* src = (mat == 0) ? wq : (mat == 1) ? wk1 : (mat == 2) ? wk2 : wk3;
      wsh[mat][rem >> 6][rem & 63] = loadf(src, rem, isbf);
    }
    __syncthreads();
    int gid = blk * 256 + t;            // 0..32767
    int qid = gid & 3;
    int n = (gid >> 2) & 4095;
    int b = gid >> 14;
    int c0 = qid * 16;
    float a[4][8];
#pragma unroll
    for (int m = 0; m < 4; ++m)
#pragma unroll
      for (int o = 0; o < 8; ++o) a[m][o] = 0.f;
    size_t base = (size_t)b * 262144 + n;
    for (int cc = 0; cc < 16; ++cc) {
      int c = c0 + cc;
      float xv = loadf(x, base + (size_t)c * 4096, isbf);
      float yv = loadf(y, base + (size_t)c * 4096, isbf);
      float zv = loadf(z, base + (size_t)c * 4096, isbf);
#pragma unroll
      for (int o = 0; o < 8; ++o) {
        a[0][o] += wsh[0][o][c] * xv;
        a[1][o] += wsh[1][o][c] * xv;
        a[2][o] += wsh[2][o][c] * yv;
        a[3][o] += wsh[3][o][c] * zv;
      }
    }
#pragma unroll
    for (int m = 0; m < 4; ++m)
#pragma unroll
      for (int o = 0; o < 8; ++o) {
        float v = a[m][o];
        v += __shfl_xor(v, 1, 64);
        v += __shfl_xor(v, 2, 64);
        a[m][o] = v;
      }
    int br = qid - 1;
    const void* bias = (qid == 0) ? bq : (qid == 1) ? bk1 : (qid == 2) ? bk2 : bk3;
    ushort* dst = (qid == 0) ? QT + (size_t)(b * 4096 + n) * 32
                             : KT + (size_t)((b * 3 + br) * 4096 + n) * 32;
    ushort row[32];
#pragma unroll
    for (int o = 0; o < 8; ++o) {
      float v = a[qid][o] + loadf(bias, o, isbf);
      row[o] = f2bf(qid == 0 ? LOG2E * v : v);
    }
#pragma unroll
    for (int o = 8; o < 32; ++o)
      row[o] = (qid > 0 && (o == 8 + 2 * br || o == 9 + 2 * br)) ? (ushort)0x3F80 : (ushort)0;
#pragma unroll
    for (int o = 0; o < 32; o += 2)
      *(unsigned int*)(dst + o) = (unsigned int)row[o] | ((unsigned int)row[o + 1] << 16);
  } else if (blk < 384) {
    // ---- Vp = sigma-permuted (wv*x + bv): slot s in 32-block holds m-offset
    //      sigma(s); here we scatter 8 consecutive m into slots s1..s1+3, s1+8..
    int tid2 = (blk - 128) * 256 + t;   // 0..65535
    int b = tid2 >> 15, c = (tid2 >> 9) & 63, m0 = (tid2 & 511) * 8;
    float acc[8], xv[8];
    float bb = loadf(bv, c, isbf);
#pragma unroll
    for (int j = 0; j < 8; ++j) acc[j] = bb;
    size_t xb = (size_t)b * 262144 + m0;
    for (int d = 0; d < 64; ++d) {
      float w = loadf(wv, c * 64 + d, isbf);
      loadf8(x, xb + (size_t)d * 4096, isbf, xv);
#pragma unroll
      for (int j = 0; j < 8; ++j) acc[j] += w * xv[j];
    }
    int M5 = m0 & ~31;                   // 32-m block base
    int o = m0 & 31;                     // 0,8,16,24
    int s1 = (o == 0) ? 0 : (o == 8) ? 16 : (o == 16) ? 20 : 4;
    s16x4 lo, hi;
#pragma unroll
    for (int j = 0; j < 4; ++j) { lo[j] = (short)f2bf(acc[j]); hi[j] = (short)f2bf(acc[4 + j]); }
    ushort* vb = Vp + (size_t)(b * 64 + c) * 4096 + M5;
    *(s16x4*)(vb + s1)     = lo;         // m-offsets o..o+3   -> slots s1..s1+3
    *(s16x4*)(vb + s1 + 8) = hi;         // m-offsets o+4..o+7 -> slots s1+8..s1+11
  } else {
    // ---- CAM gram partials e_part[b][k][ns16][64][64]
    int r2 = blk - 384;
    int ns = r2 & 15, r = r2 >> 4;      // r in 0..5
    int k = r % 3, b = r / 3;
    const void* A = x;
    const void* B = (k == 0) ? x : (k == 1) ? y : z;
    size_t boff = (size_t)b * 262144;
    int w = t >> 6, l = t & 63;
    int l15 = l & 15, lh = l >> 4;
    int cbase = 16 * w;
    f32x4 acc[4];
#pragma unroll
    for (int i = 0; i < 4; ++i) acc[i] = (f32x4){0.f, 0.f, 0.f, 0.f};
    int n0 = ns * 256;
    for (int step = 0; step < 8; ++step) {
      int nb = n0 + step * 32;
      bf16x8 af = load8(A, boff + (size_t)(cbase + l15) * 4096 + nb + lh * 8, isbf);
#pragma unroll
      for (int dt = 0; dt < 4; ++dt) {
        bf16x8 bfr = load8(B, boff + (size_t)(dt * 16 + l15) * 4096 + nb + lh * 8, isbf);
        acc[dt] = MFMA16(af, bfr, acc[dt]);
      }
    }
    float* out = e_part + (size_t)(((b * 3 + k) * 16 + ns) * 64) * 64;
#pragma unroll
    for (int dt = 0; dt < 4; ++dt)
#pragma unroll
      for (int rr = 0; rr < 4; ++rr) {
        int c = cbase + lh * 4 + rr, d = dt * 16 + l15;
        out[c * 64 + d] = acc[dt][rr];
      }
  }
}

// ---------------------------------------------------------------------------
// KB: PAM pass 1 — S_part[sl][(b*3+br)*4096+m] = sum_{n slice} exp2(Ehat). 1536 blocks.
__global__ __launch_bounds__(256) void k_pass1(
    const ushort* __restrict__ QT, const ushort* __restrict__ KT, float* __restrict__ S_part)
{
  int blk = blockIdx.x, t = threadIdx.x;
  int sl = blk & 3, mc = (blk >> 2) & 63, r3 = blk >> 8;  // r3 in 0..5
  int br = r3 % 3, b = r3 / 3;
  int w = t >> 6, l = t & 63;
  int l15 = l & 15, lh = l >> 4;
  int mbase = mc * 64 + w * 16;
  bf16x8 qf = *(const bf16x8*)(QT + (size_t)(b * 4096 + mbase + l15) * 32 + lh * 8);
  const ushort* Kb = KT + (size_t)((b * 3 + br) * 4096) * 32;
  float s = 0.f;
  int ns0 = sl * 64;
#pragma unroll 4
  for (int ns = ns0; ns < ns0 + 64; ++ns) {
    bf16x8 kf = *(const bf16x8*)(Kb + (size_t)(ns * 16 + l15) * 32 + lh * 8);
    f32x4 d = MFMA16(kf, qf, ((f32x4){0.f, 0.f, 0.f, 0.f}));
    s += EX2(d[0]) + EX2(d[1]) + EX2(d[2]) + EX2(d[3]);
  }
  s += __shfl_xor(s, 16, 64);
  s += __shfl_xor(s, 32, 64);
  if (l < 16) S_part[sl * 24576 + (b * 3 + br) * 4096 + mbase + l] = s;
}

// ---------------------------------------------------------------------------
// KC: blocks 0..1023: PAM pass 2, P in registers.
//     Self-patch QT L-slots for own ms-slice (identical-value benign race),
//     then per 32-m chunk: E-MFMA -> EX2 -> cvt_pk -> shfl_xor(32) -> PV MFMA.
//     blocks 1024..1025: CAM small (inline e_part reduce, reg Atot, Wfull, biasv).
__global__ __launch_bounds__(256) void k_pam_out(
    ushort* __restrict__ QT, const ushort* __restrict__ KT, const ushort* __restrict__ Vp,
    const float* __restrict__ S_part, const float* __restrict__ e_part,
    const void* __restrict__ x,
    const void* __restrict__ cam_wl, const void* __restrict__ cam_bl, const void* __restrict__ cam_gamma,
    const void* __restrict__ pam_wl, const void* __restrict__ pam_bl, const void* __restrict__ pam_gamma,
    ushort* __restrict__ Wfull, float* __restrict__ biasv,
    ushort* __restrict__ pam_part)
{
  __shared__ float erow[64][65];
  __shared__ int sflag;
  int blk = blockIdx.x, t = threadIdx.x;

  if (blk >= 1024) {
    // ---------------- CAM small ----------------
    int isbf = detect_isbf((const unsigned int*)x, &sflag);
    int b = blk - 1024;
    int r = t >> 2, q = t & 3;
    float atot[16];
#pragma unroll
    for (int j = 0; j < 16; ++j) atot[j] = 0.f;
    for (int k = 0; k < 3; ++k) {
      const float* ep = e_part + (size_t)((b * 3 + k) * 16) * 4096;
      for (int i = t; i < 4096; i += 256) {
        float s = 0.f;
#pragma unroll
        for (int ks = 0; ks < 16; ++ks) s += ep[ks * 4096 + i];
        erow[i >> 6][i & 63] = s;
      }
      __syncthreads();
      float ev[16];
      float mn = 1e30f;
#pragma unroll
      for (int j = 0; j < 16; ++j) { ev[j] = erow[r][q * 16 + j]; mn = fminf(mn, ev[j]); }
      mn = fminf(mn, __shfl_xor(mn, 1, 64));
      mn = fminf(mn, __shfl_xor(mn, 2, 64));
      float s = 0.f;
#pragma unroll
      for (int j = 0; j < 16; ++j) { ev[j] = __expf(mn - ev[j]); s += ev[j]; }
      s += __shfl_xor(s, 1, 64);
      s += __shfl_xor(s, 2, 64);
      float inv = 1.0f / s;
#pragma unroll
      for (int j = 0; j < 16; ++j) atot[j] += ev[j] * inv;
      __syncthreads();
    }
    // materialize Atot into erow (reuse) for the cross-row matmul
    erow[r][q * 16 + 0] = atot[0];
#pragma unroll
    for (int j = 0; j < 16; ++j) erow[r][q * 16 + j] = atot[j];
    __syncthreads();
    float gc = loadf(cam_gamma, 0, isbf), gp = loadf(pam_gamma, 0, isbf);
    int c = t >> 2, d0 = (t & 3) * 16;
    float a[16];
#pragma unroll
    for (int i = 0; i < 16; ++i) a[i] = 0.f;
    for (int e = 0; e < 64; ++e) {
      float wv = loadf(cam_wl, c * 64 + e, isbf);
#pragma unroll
      for (int i = 0; i < 16; ++i) a[i] += wv * erow[e][d0 + i];
    }
#pragma unroll
    for (int i = 0; i < 16; ++i) {
      int d = d0 + i;
      Wfull[(size_t)(b * 64 + c) * 128 + d]      = f2bf(gc * a[i]);
      Wfull[(size_t)(b * 64 + c) * 128 + 64 + d] = f2bf(gp * loadf(pam_wl, c * 64 + d, isbf));
    }
    if (b == 0 && t < 64) biasv[t] = gp * loadf(pam_bl, t, isbf) + gc * loadf(cam_bl, t, isbf);
    return;
  }

  // ---------------- PAM pass 2 ----------------
  int ms = blk & 3, nt = (blk >> 2) & 127, b = blk >> 9;
  // self-patch QT L-slots for this (b, ms) slice; values identical across blocks
  for (int i = t; i < 1024; i += 256) {
    int m = ms * 1024 + i;
    ushort* qrow = QT + (size_t)(b * 4096 + m) * 32;
#pragma unroll
    for (int br = 0; br < 3; ++br) {
      int idx = (b * 3 + br) * 4096 + m;
      float S = S_part[idx] + S_part[24576 + idx] + S_part[49152 + idx] + S_part[73728 + idx];
      float nL = -__builtin_amdgcn_logf(S);   // -log2(S)
      ushort cc = f2bf(nL);
      qrow[8 + 2 * br] = cc;
      qrow[9 + 2 * br] = f2bf(nL - bf2f(cc));
    }
  }
  __syncthreads();   // drains vmcnt; own-block loads below hit L2 with patched rows

  int w = t >> 6, l = t & 63;
  int l15 = l & 15, lh = l >> 4;
  int n0 = nt * 32;

  bf16x8 kf[3][2];
#pragma unroll
  for (int br = 0; br < 3; ++br)
#pragma unroll
    for (int n16 = 0; n16 < 2; ++n16)
      kf[br][n16] = *(const bf16x8*)(KT + (size_t)((b * 3 + br) * 4096 + n0 + n16 * 16 + l15) * 32 + lh * 8);

  f32x4 acc[2];
  acc[0] = (f32x4){0.f, 0.f, 0.f, 0.f};
  acc[1] = (f32x4){0.f, 0.f, 0.f, 0.f};
  const ushort* Vb = Vp + (size_t)(b * 64 + 16 * w + l15) * 4096;
  const f32x4 Z = (f32x4){0.f, 0.f, 0.f, 0.f};

  for (int ch = 0; ch < 32; ++ch) {
    int mch = ms * 1024 + ch * 32;
    const ushort* qbase = QT + (size_t)(b * 4096 + mch + l15) * 32 + lh * 8;
    bf16x8 qf0 = *(const bf16x8*)(qbase);
    bf16x8 qf1 = *(const bf16x8*)(qbase + 512);   // +16 rows * 32
    bf16x8 vf  = *(const bf16x8*)(Vb + mch + lh * 8);
#pragma unroll
    for (int n16 = 0; n16 < 2; ++n16) {
      f32x4 dA0 = MFMA16(qf0, kf[0][n16], Z);
      f32x4 dA1 = MFMA16(qf0, kf[1][n16], Z);
      f32x4 dA2 = MFMA16(qf0, kf[2][n16], Z);
      f32x4 dB0 = MFMA16(qf1, kf[0][n16], Z);
      f32x4 dB1 = MFMA16(qf1, kf[1][n16], Z);
      f32x4 dB2 = MFMA16(qf1, kf[2][n16], Z);
      float plo[4], phi[4];
#pragma unroll
      for (int rr = 0; rr < 4; ++rr) {
        plo[rr] = EX2(dA0[rr]) + EX2(dA1[rr]) + EX2(dA2[rr]);
        phi[rr] = EX2(dB0[rr]) + EX2(dB1[rr]) + EX2(dB2[rr]);
      }
      unsigned int u0, u1, q0, q1;
      asm("v_cvt_pk_bf16_f32 %0, %1, %2" : "=v"(u0) : "v"(plo[0]), "v"(plo[1]));
      asm("v_cvt_pk_bf16_f32 %0, %1, %2" : "=v"(u1) : "v"(plo[2]), "v"(plo[3]));
      asm("v_cvt_pk_bf16_f32 %0, %1, %2" : "=v"(q0) : "v"(phi[0]), "v"(phi[1]));
      asm("v_cvt_pk_bf16_f32 %0, %1, %2" : "=v"(q1) : "v"(phi[2]), "v"(phi[3]));
      unsigned int t0 = (unsigned int)__shfl_xor((int)q0, 32, 64);
      unsigned int t1 = (unsigned int)__shfl_xor((int)q1, 32, 64);
      union { unsigned int uw[4]; bf16x8 v; } pf;
      pf.uw[0] = u0; pf.uw[1] = u1; pf.uw[2] = t0; pf.uw[3] = t1;
      acc[n16] = MFMA16(vf, pf.v, acc[n16]);
    }
  }
  ushort* outp = pam_part + (size_t)((b * 4 + ms) * 64) * 4096;
#pragma unroll
  for (int n16 = 0; n16 < 2; ++n16)
#pragma unroll
    for (int r = 0; r < 4; ++r) {
      int c = 16 * w + lh * 4 + r, n = n0 + n16 * 16 + l15;
      outp[(size_t)c * 4096 + n] = f2bf(acc[n16][r]);
    }
}

// ---------------------------------------------------------------------------
// KE: final — out = 2x + M_b*x + (gp*Wp)*pam_out + biasv. 128 blocks.
__global__ __launch_bounds__(256) void k_final(
    const void* __restrict__ x, const ushort* __restrict__ pam_part,
    const ushort* __restrict__ Wfull, const float* __restrict__ biasv,
    void* __restrict__ outv)
{
  __shared__ ushort u[64 * 128];
  __shared__ int sflag;
  int isbf = detect_isbf((const unsigned int*)x, &sflag);
  int blk = blockIdx.x;
  int nt = blk & 63, b = blk >> 6;
  int t = threadIdx.x;
  int n0 = nt * 64;
  int d = t >> 2, nl0 = (t & 3) * 16;
  size_t xbase = (size_t)(b * 64 + d) * 4096 + n0 + nl0;
#pragma unroll
  for (int i = 0; i < 16; ++i) {
    int nl = nl0 + i;
    int byte = (nl * 256 + d * 2) ^ ((nl & 7) << 4);
    *(ushort*)((char*)u + byte) = f2bf(loadf(x, xbase + i, isbf));
  }
  const ushort* pp = pam_part + (size_t)(b * 256 + d) * 4096 + n0 + nl0;
#pragma unroll
  for (int i = 0; i < 16; ++i) {
    float s = bf2f(pp[i]) + bf2f(pp[262144 + i]) + bf2f(pp[524288 + i]) + bf2f(pp[786432 + i]);
    int nl = nl0 + i;
    int byte = (nl * 256 + (64 + d) * 2) ^ ((nl & 7) << 4);
    *(ushort*)((char*)u + byte) = f2bf(s);
  }
  __syncthreads();

  int w = t >> 6, l = t & 63, l15 = l & 15, lh = l >> 4;
  f32x4 acc[4];
#pragma unroll
  for (int i = 0; i < 4; ++i) acc[i] = (f32x4){0.f, 0.f, 0.f, 0.f};
#pragma unroll
  for (int ks = 0; ks < 4; ++ks) {
    bf16x8 af = *(const bf16x8*)(Wfull + (size_t)(b * 64 + 16 * w + l15) * 128 + ks * 32 + lh * 8);
#pragma unroll
    for (int nt4 = 0; nt4 < 4; ++nt4) {
      int nl = nt4 * 16 + l15;
      int byte = (nl * 256 + (ks * 32 + lh * 8) * 2) ^ ((nl & 7) << 4);
      bf16x8 bfr = *(const bf16x8*)((const char*)u + byte);
      acc[nt4] = MFMA16(af, bfr, acc[nt4]);
    }
  }
#pragma unroll
  for (int nt4 = 0; nt4 < 4; ++nt4)
#pragma unroll
    for (int r = 0; r < 4; ++r) {
      int c = 16 * w + lh * 4 + r, nl = nt4 * 16 + l15;
      size_t xidx = (size_t)(b * 64 + c) * 4096 + n0 + nl;
      float xv = loadf(x, xidx, isbf);
      float v = acc[nt4][r] + 2.0f * xv + biasv[c];
      if (isbf) ((ushort*)outv)[xidx] = f2bf(v);
      else      ((float*)outv)[xidx]  = v;
    }
}

// ---------------------------------------------------------------------------
extern "C" void kernel_launch(void* const* d_in, const int* in_sizes, int n_in,
                              void* d_out, int out_size, void* d_ws, size_t ws_size,
                              hipStream_t stream) {
  const void* x   = d_in[0];
  const void* y   = d_in[1];
  const void* z   = d_in[2];
  const void* wq  = d_in[3];
  const void* bq  = d_in[4];
  const void* wk1 = d_in[5];
  const void* bk1 = d_in[6];
  const void* wk2 = d_in[7];
  const void* bk2 = d_in[8];
  const void* wk3 = d_in[9];
  const void* bk3 = d_in[10];
  const void* wv  = d_in[11];
  const void* bv  = d_in[12];
  const void* pwl = d_in[13];
  const void* pbl = d_in[14];
  const void* pg  = d_in[15];
  const void* cwl = d_in[16];
  const void* cbl = d_in[17];
  const void* cg  = d_in[18];

  char* ws = (char*)d_ws;
  ushort* QT      = (ushort*)(ws + 0);         //  512 KB  [2][4096][32] bf16
  ushort* KT      = (ushort*)(ws + 524288);    // 1536 KB  [6][4096][32] bf16
  ushort* Vp      = (ushort*)(ws + 2097152);   // 1024 KB  [2][64][4096] bf16 (sigma)
  float*  S_part  = (float*) (ws + 3145728);   //  384 KB  [4][2*3*4096] f32
  float*  e_part  = (float*) (ws + 3538944);   // 1536 KB  [2][3][16][64][64] f32
  ushort* pam_prt = (ushort*)(ws + 5111808);   // 4096 KB  [2][4][64][4096] bf16
  ushort* Wfull   = (ushort*)(ws + 9306112);   //   32 KB  [2][64][128] bf16
  float*  biasv   = (float*) (ws + 9338880);   //  256 B   [64] f32

  k_prep_all<<< 480, 256, 0, stream>>>(x, y, z, wq, bq, wk1, bk1, wk2, bk2, wk3, bk3,
                                       wv, bv, QT, KT, Vp, e_part);
  k_pass1   <<<1536, 256, 0, stream>>>(QT, KT, S_part);
  k_pam_out <<<1026, 256, 0, stream>>>(QT, KT, Vp, S_part, e_part, x,
                                       cwl, cbl, cg, pwl, pbl, pg, Wfull, biasv, pam_prt);
  k_final   <<< 128, 256, 0, stream>>>(x, pam_prt, Wfull, biasv, d_out);
}

// Round 7
// 136.340 us; speedup vs baseline: 1.0152x; 1.0152x over previous
//
#include <hip/hip_runtime.h>
#include <hip/hip_bf16.h>

// MsPAM+CAM fused, MI355X gfx950.  B=2, C=64, H=W=64, N=4096, Cq=8.
// 4-kernel pipeline. Softmax normalization folded into MFMA via spare Q/K
// slots (Q 8..13 = -log2(S) split pair, K one-hot 1.0), patched per-block.
// PAM pass2: P fully in registers. Waves partition m (32 m per wave per chunk);
// sigma' k-permutation makes the cross-half exchange = v_permlane32_swap_b32;
// per-wave PV partials reduced across waves once via LDS at kernel end.

typedef __attribute__((ext_vector_type(8))) short bf16x8;
typedef __attribute__((ext_vector_type(4))) short s16x4;
typedef __attribute__((ext_vector_type(4))) float f32x4;

#define MFMA16(a, b, c) __builtin_amdgcn_mfma_f32_16x16x32_bf16(a, b, c, 0, 0, 0)
#define EX2(x) __builtin_amdgcn_exp2f(x)
#define LOG2E 1.4426950408889634f

__device__ __forceinline__ float bf2f(ushort u) {
  union { unsigned int i; float f; } v; v.i = ((unsigned int)u) << 16; return v.f;
}
__device__ __forceinline__ ushort f2bf(float f) {  // RNE
  union { float f; unsigned int i; } v; v.f = f;
  unsigned int r = v.i + 0x7FFFu + ((v.i >> 16) & 1u);
  return (ushort)(r >> 16);
}
__device__ __forceinline__ float loadf(const void* p, size_t i, int isbf) {
  return isbf ? bf2f(((const ushort*)p)[i]) : ((const float*)p)[i];
}
__device__ __forceinline__ bf16x8 load8(const void* p, size_t i, int isbf) {
  if (isbf) return *(const bf16x8*)((const ushort*)p + i);
  const float* f = (const float*)p + i;
  bf16x8 r;
#pragma unroll
  for (int j = 0; j < 8; ++j) r[j] = (short)f2bf(f[j]);
  return r;
}
__device__ __forceinline__ void loadf8(const void* p, size_t i, int isbf, float* o) {
  if (isbf) {
    bf16x8 v = *(const bf16x8*)((const ushort*)p + i);
#pragma unroll
    for (int j = 0; j < 8; ++j) o[j] = bf2f((ushort)v[j]);
  } else {
    const float* f = (const float*)p + i;
#pragma unroll
    for (int j = 0; j < 8; ++j) o[j] = f[j];
  }
}
// per-block dtype detect: bf16-packed x has low-16 exponent bits in [120,133].
__device__ __forceinline__ int detect_isbf(const unsigned int* xw, int* sflag) {
  int t = threadIdx.x;
  if (t < 64) {
    unsigned int w1 = xw[t], w2 = xw[64 + t];
    unsigned int e1 = (w1 >> 7) & 0xFFu, e2 = (w2 >> 7) & 0xFFu;
    unsigned long long b1 = __ballot(e1 >= 120u && e1 <= 133u);
    unsigned long long b2 = __ballot(e2 >= 120u && e2 <= 133u);
    if (t == 0) *sflag = (__popcll(b1) + __popcll(b2) > 64) ? 1 : 0;
  }
  __syncthreads();
  return *sflag;
}

// ---------------------------------------------------------------------------
// KA: fused prep. blocks 0..127: Q/K convs -> QT/KT; 128..383: Vp (sigma'-
//     permuted V conv); 384..479: CAM gram partials e_part.
__global__ __launch_bounds__(256) void k_prep_all(
    const void* __restrict__ x, const void* __restrict__ y, const void* __restrict__ z,
    const void* __restrict__ wq, const void* __restrict__ bq,
    const void* __restrict__ wk1, const void* __restrict__ bk1,
    const void* __restrict__ wk2, const void* __restrict__ bk2,
    const void* __restrict__ wk3, const void* __restrict__ bk3,
    const void* __restrict__ wv, const void* __restrict__ bv,
    ushort* __restrict__ QT, ushort* __restrict__ KT, ushort* __restrict__ Vp,
    float* __restrict__ e_part)
{
  __shared__ float wsh[4][8][64];
  __shared__ int sflag;
  int isbf = detect_isbf((const unsigned int*)x, &sflag);
  int blk = blockIdx.x, t = threadIdx.x;

  if (blk < 128) {
    // ---- Q/K1/K2/K3 convs, 4 threads per n (16 c each) + quad shfl reduce
    for (int i = t; i < 2048; i += 256) {
      int mat = i >> 9, rem = i & 511;
      const void* src = (mat == 0) ? wq : (mat == 1) ? wk1 : (mat == 2) ? wk2 : wk3;
      wsh[mat][rem >> 6][rem & 63] = loadf(src, rem, isbf);
    }
    __syncthreads();
    int gid = blk * 256 + t;            // 0..32767
    int qid = gid & 3;
    int n = (gid >> 2) & 4095;
    int b = gid >> 14;
    int c0 = qid * 16;
    float a[4][8];
#pragma unroll
    for (int m = 0; m < 4; ++m)
#pragma unroll
      for (int o = 0; o < 8; ++o) a[m][o] = 0.f;
    size_t base = (size_t)b * 262144 + n;
    for (int cc = 0; cc < 16; ++cc) {
      int c = c0 + cc;
      float xv = loadf(x, base + (size_t)c * 4096, isbf);
      float yv = loadf(y, base + (size_t)c * 4096, isbf);
      float zv = loadf(z, base + (size_t)c * 4096, isbf);
#pragma unroll
      for (int o = 0; o < 8; ++o) {
        a[0][o] += wsh[0][o][c] * xv;
        a[1][o] += wsh[1][o][c] * xv;
        a[2][o] += wsh[2][o][c] * yv;
        a[3][o] += wsh[3][o][c] * zv;
      }
    }
#pragma unroll
    for (int m = 0; m < 4; ++m)
#pragma unroll
      for (int o = 0; o < 8; ++o) {
        float v = a[m][o];
        v += __shfl_xor(v, 1, 64);
        v += __shfl_xor(v, 2, 64);
        a[m][o] = v;
      }
    int br = qid - 1;
    const void* bias = (qid == 0) ? bq : (qid == 1) ? bk1 : (qid == 2) ? bk2 : bk3;
    ushort* dst = (qid == 0) ? QT + (size_t)(b * 4096 + n) * 32
                             : KT + (size_t)((b * 3 + br) * 4096 + n) * 32;
    ushort row[32];
#pragma unroll
    for (int o = 0; o < 8; ++o) {
      float v = a[qid][o] + loadf(bias, o, isbf);
      row[o] = f2bf(qid == 0 ? LOG2E * v : v);
    }
#pragma unroll
    for (int o = 8; o < 32; ++o)
      row[o] = (qid > 0 && (o == 8 + 2 * br || o == 9 + 2 * br)) ? (ushort)0x3F80 : (ushort)0;
#pragma unroll
    for (int o = 0; o < 32; o += 2)
      *(unsigned int*)(dst + o) = (unsigned int)row[o] | ((unsigned int)row[o + 1] << 16);
  } else if (blk < 384) {
    // ---- Vp = sigma'-permuted (wv*x + bv). For each 32-m block, slot k holds
    //      V[m(k)] where m-quads map: kq = {0,2,1,3,4,6,5,7}[mq].
    int tid2 = (blk - 128) * 256 + t;   // 0..65535
    int b = tid2 >> 15, c = (tid2 >> 9) & 63, m0 = (tid2 & 511) * 8;
    float acc[8], xv[8];
    float bb = loadf(bv, c, isbf);
#pragma unroll
    for (int j = 0; j < 8; ++j) acc[j] = bb;
    size_t xb = (size_t)b * 262144 + m0;
    for (int d = 0; d < 64; ++d) {
      float w = loadf(wv, c * 64 + d, isbf);
      loadf8(x, xb + (size_t)d * 4096, isbf, xv);
#pragma unroll
      for (int j = 0; j < 8; ++j) acc[j] += w * xv[j];
    }
    int M5 = m0 & ~31;                   // 32-m block base
    int o = m0 & 31;                     // 0,8,16,24
    int s1 = (o & 16) | ((o & 8) >> 1);  // 0->0, 8->4, 16->16, 24->20
    s16x4 lo, hi;
#pragma unroll
    for (int j = 0; j < 4; ++j) { lo[j] = (short)f2bf(acc[j]); hi[j] = (short)f2bf(acc[4 + j]); }
    ushort* vb = Vp + (size_t)(b * 64 + c) * 4096 + M5;
    *(s16x4*)(vb + s1)     = lo;         // m o..o+3   -> slots s1..s1+3
    *(s16x4*)(vb + s1 + 8) = hi;         // m o+4..o+7 -> slots s1+8..s1+11
  } else {
    // ---- CAM gram partials e_part[b][k][ns16][64][64]
    int r2 = blk - 384;
    int ns = r2 & 15, r = r2 >> 4;      // r in 0..5
    int k = r % 3, b = r / 3;
    const void* A = x;
    const void* B = (k == 0) ? x : (k == 1) ? y : z;
    size_t boff = (size_t)b * 262144;
    int w = t >> 6, l = t & 63;
    int l15 = l & 15, lh = l >> 4;
    int cbase = 16 * w;
    f32x4 acc[4];
#pragma unroll
    for (int i = 0; i < 4; ++i) acc[i] = (f32x4){0.f, 0.f, 0.f, 0.f};
    int n0 = ns * 256;
    for (int step = 0; step < 8; ++step) {
      int nb = n0 + step * 32;
      bf16x8 af = load8(A, boff + (size_t)(cbase + l15) * 4096 + nb + lh * 8, isbf);
#pragma unroll
      for (int dt = 0; dt < 4; ++dt) {
        bf16x8 bfr = load8(B, boff + (size_t)(dt * 16 + l15) * 4096 + nb + lh * 8, isbf);
        acc[dt] = MFMA16(af, bfr, acc[dt]);
      }
    }
    float* out = e_part + (size_t)(((b * 3 + k) * 16 + ns) * 64) * 64;
#pragma unroll
    for (int dt = 0; dt < 4; ++dt)
#pragma unroll
      for (int rr = 0; rr < 4; ++rr) {
        int c = cbase + lh * 4 + rr, d = dt * 16 + l15;
        out[c * 64 + d] = acc[dt][rr];
      }
  }
}

// ---------------------------------------------------------------------------
// KB: PAM pass 1 — S_part[sl][(b*3+br)*4096+m] = sum_{n slice} exp2(Ehat). 1536 blocks.
__global__ __launch_bounds__(256) void k_pass1(
    const ushort* __restrict__ QT, const ushort* __restrict__ KT, float* __restrict__ S_part)
{
  int blk = blockIdx.x, t = threadIdx.x;
  int sl = blk & 3, mc = (blk >> 2) & 63, r3 = blk >> 8;  // r3 in 0..5
  int br = r3 % 3, b = r3 / 3;
  int w = t >> 6, l = t & 63;
  int l15 = l & 15, lh = l >> 4;
  int mbase = mc * 64 + w * 16;
  bf16x8 qf = *(const bf16x8*)(QT + (size_t)(b * 4096 + mbase + l15) * 32 + lh * 8);
  const ushort* Kb = KT + (size_t)((b * 3 + br) * 4096) * 32;
  float s = 0.f;
  int ns0 = sl * 64;
#pragma unroll 4
  for (int ns = ns0; ns < ns0 + 64; ++ns) {
    bf16x8 kf = *(const bf16x8*)(Kb + (size_t)(ns * 16 + l15) * 32 + lh * 8);
    f32x4 d = MFMA16(kf, qf, ((f32x4){0.f, 0.f, 0.f, 0.f}));
    s += EX2(d[0]) + EX2(d[1]) + EX2(d[2]) + EX2(d[3]);
  }
  s += __shfl_xor(s, 16, 64);
  s += __shfl_xor(s, 32, 64);
  if (l < 16) S_part[sl * 24576 + (b * 3 + br) * 4096 + mbase + l] = s;
}

// ---------------------------------------------------------------------------
// KC: blocks 0..2047: PAM pass 2 (b x 256 nt x 4 ms). Waves partition m.
//     Self-patch QT L-slots for own ms-slice, then per 128-m chunk each wave:
//     E-MFMA(32 m x 16 n) -> EX2 -> cvt_pk -> permlane32_swap -> 4 PV MFMA.
//     Cross-wave reduce via LDS at end. blocks 2048..2049: CAM small.
__global__ __launch_bounds__(256) void k_pam_out(
    ushort* __restrict__ QT, const ushort* __restrict__ KT, const ushort* __restrict__ Vp,
    const float* __restrict__ S_part, const float* __restrict__ e_part,
    const void* __restrict__ x,
    const void* __restrict__ cam_wl, const void* __restrict__ cam_bl, const void* __restrict__ cam_gamma,
    const void* __restrict__ pam_wl, const void* __restrict__ pam_bl, const void* __restrict__ pam_gamma,
    ushort* __restrict__ Wfull, float* __restrict__ biasv,
    ushort* __restrict__ pam_part)
{
  __shared__ float smem[4 * 64 * 17];   // pam: red[4][64][17]; cam: erow[64][65]
  __shared__ int sflag;
  int blk = blockIdx.x, t = threadIdx.x;

  if (blk >= 2048) {
    // ---------------- CAM small ----------------
    float (*erow)[65] = (float(*)[65])smem;
    int isbf = detect_isbf((const unsigned int*)x, &sflag);
    int b = blk - 2048;
    int r = t >> 2, q = t & 3;
    float atot[16];
#pragma unroll
    for (int j = 0; j < 16; ++j) atot[j] = 0.f;
    for (int k = 0; k < 3; ++k) {
      const float* ep = e_part + (size_t)((b * 3 + k) * 16) * 4096;
      for (int i = t; i < 4096; i += 256) {
        float s = 0.f;
#pragma unroll
        for (int ks = 0; ks < 16; ++ks) s += ep[ks * 4096 + i];
        erow[i >> 6][i & 63] = s;
      }
      __syncthreads();
      float ev[16];
      float mn = 1e30f;
#pragma unroll
      for (int j = 0; j < 16; ++j) { ev[j] = erow[r][q * 16 + j]; mn = fminf(mn, ev[j]); }
      mn = fminf(mn, __shfl_xor(mn, 1, 64));
      mn = fminf(mn, __shfl_xor(mn, 2, 64));
      float s = 0.f;
#pragma unroll
      for (int j = 0; j < 16; ++j) { ev[j] = __expf(mn - ev[j]); s += ev[j]; }
      s += __shfl_xor(s, 1, 64);
      s += __shfl_xor(s, 2, 64);
      float inv = 1.0f / s;
#pragma unroll
      for (int j = 0; j < 16; ++j) atot[j] += ev[j] * inv;
      __syncthreads();
    }
#pragma unroll
    for (int j = 0; j < 16; ++j) erow[r][q * 16 + j] = atot[j];
    __syncthreads();
    float gc = loadf(cam_gamma, 0, isbf), gp = loadf(pam_gamma, 0, isbf);
    int c = t >> 2, d0 = (t & 3) * 16;
    float a[16];
#pragma unroll
    for (int i = 0; i < 16; ++i) a[i] = 0.f;
    for (int e = 0; e < 64; ++e) {
      float wv = loadf(cam_wl, c * 64 + e, isbf);
#pragma unroll
      for (int i = 0; i < 16; ++i) a[i] += wv * erow[e][d0 + i];
    }
#pragma unroll
    for (int i = 0; i < 16; ++i) {
      int d = d0 + i;
      Wfull[(size_t)(b * 64 + c) * 128 + d]      = f2bf(gc * a[i]);
      Wfull[(size_t)(b * 64 + c) * 128 + 64 + d] = f2bf(gp * loadf(pam_wl, c * 64 + d, isbf));
    }
    if (b == 0 && t < 64) biasv[t] = gp * loadf(pam_bl, t, isbf) + gc * loadf(cam_bl, t, isbf);
    return;
  }

  // ---------------- PAM pass 2 ----------------
  int ms = blk & 3, nt = (blk >> 2) & 255, b = blk >> 10;
  // self-patch QT L-slots for this (b, ms) slice; identical values across blocks
  for (int i = t; i < 1024; i += 256) {
    int m = ms * 1024 + i;
    ushort* qrow = QT + (size_t)(b * 4096 + m) * 32;
#pragma unroll
    for (int br = 0; br < 3; ++br) {
      int idx = (b * 3 + br) * 4096 + m;
      float S = S_part[idx] + S_part[24576 + idx] + S_part[49152 + idx] + S_part[73728 + idx];
      float nL = -__builtin_amdgcn_logf(S);   // -log2(S)
      ushort cc = f2bf(nL);
      qrow[8 + 2 * br] = cc;
      qrow[9 + 2 * br] = f2bf(nL - bf2f(cc));
    }
  }
  __syncthreads();

  int w = t >> 6, l = t & 63;
  int l15 = l & 15, lh = l >> 4;
  int n0 = nt * 16;

  bf16x8 kf[3];
#pragma unroll
  for (int br = 0; br < 3; ++br)
    kf[br] = *(const bf16x8*)(KT + (size_t)((b * 3 + br) * 4096 + n0 + l15) * 32 + lh * 8);

  f32x4 acc[4];
#pragma unroll
  for (int i = 0; i < 4; ++i) acc[i] = (f32x4){0.f, 0.f, 0.f, 0.f};
  const f32x4 Z = (f32x4){0.f, 0.f, 0.f, 0.f};
  const ushort* vrow = Vp + (size_t)(b * 64 + l15) * 4096;

  for (int ch = 0; ch < 8; ++ch) {
    int mbase = ms * 1024 + ch * 128 + 32 * w;    // wave-private 32-m slice
    const ushort* qb = QT + (size_t)(b * 4096 + mbase + l15) * 32 + lh * 8;
    bf16x8 qf0 = *(const bf16x8*)(qb);
    bf16x8 qf1 = *(const bf16x8*)(qb + 512);      // +16 rows
    f32x4 dA0 = MFMA16(qf0, kf[0], Z);
    f32x4 dA1 = MFMA16(qf0, kf[1], Z);
    f32x4 dA2 = MFMA16(qf0, kf[2], Z);
    f32x4 dB0 = MFMA16(qf1, kf[0], Z);
    f32x4 dB1 = MFMA16(qf1, kf[1], Z);
    f32x4 dB2 = MFMA16(qf1, kf[2], Z);
    float plo[4], phi[4];
#pragma unroll
    for (int rr = 0; rr < 4; ++rr) {
      plo[rr] = EX2(dA0[rr]) + EX2(dA1[rr]) + EX2(dA2[rr]);
      phi[rr] = EX2(dB0[rr]) + EX2(dB1[rr]) + EX2(dB2[rr]);
    }
    unsigned int a0, a1, b0, b1;
    asm("v_cvt_pk_bf16_f32 %0, %1, %2" : "=v"(a0) : "v"(plo[0]), "v"(plo[1]));
    asm("v_cvt_pk_bf16_f32 %0, %1, %2" : "=v"(a1) : "v"(plo[2]), "v"(plo[3]));
    asm("v_cvt_pk_bf16_f32 %0, %1, %2" : "=v"(b0) : "v"(phi[0]), "v"(phi[1]));
    asm("v_cvt_pk_bf16_f32 %0, %1, %2" : "=v"(b1) : "v"(phi[2]), "v"(phi[3]));
    // a' = {a.lo-half, b.lo-half}, b' = {a.hi-half, b.hi-half} across lane 32 split
    asm("v_permlane32_swap_b32 %0, %1" : "+v"(a0), "+v"(b0));
    asm("v_permlane32_swap_b32 %0, %1" : "+v"(a1), "+v"(b1));
    union { unsigned int uw[4]; bf16x8 v; } pf;
    pf.uw[0] = a0; pf.uw[1] = a1; pf.uw[2] = b0; pf.uw[3] = b1;
#pragma unroll
    for (int ct = 0; ct < 4; ++ct) {
      bf16x8 vf = *(const bf16x8*)(vrow + (size_t)ct * 16 * 4096 + mbase + lh * 8);
      acc[ct] = MFMA16(vf, pf.v, acc[ct]);
    }
  }

  // cross-wave reduction: red[w][c][n], padded stride 17
  float* red = smem;
#pragma unroll
  for (int ct = 0; ct < 4; ++ct)
#pragma unroll
    for (int rr = 0; rr < 4; ++rr)
      red[w * 1088 + (ct * 16 + lh * 4 + rr) * 17 + l15] = acc[ct][rr];
  __syncthreads();
  {
    int c = t >> 2, nb = (t & 3) * 4;
    float s0 = red[c * 17 + nb + 0] + red[1088 + c * 17 + nb + 0] + red[2176 + c * 17 + nb + 0] + red[3264 + c * 17 + nb + 0];
    float s1 = red[c * 17 + nb + 1] + red[1088 + c * 17 + nb + 1] + red[2176 + c * 17 + nb + 1] + red[3264 + c * 17 + nb + 1];
    float s2 = red[c * 17 + nb + 2] + red[1088 + c * 17 + nb + 2] + red[2176 + c * 17 + nb + 2] + red[3264 + c * 17 + nb + 2];
    float s3 = red[c * 17 + nb + 3] + red[1088 + c * 17 + nb + 3] + red[2176 + c * 17 + nb + 3] + red[3264 + c * 17 + nb + 3];
    uint2 o;
    asm("v_cvt_pk_bf16_f32 %0, %1, %2" : "=v"(o.x) : "v"(s0), "v"(s1));
    asm("v_cvt_pk_bf16_f32 %0, %1, %2" : "=v"(o.y) : "v"(s2), "v"(s3));
    *(uint2*)(pam_part + (size_t)((b * 4 + ms) * 64 + c) * 4096 + n0 + nb) = o;
  }
}

// ---------------------------------------------------------------------------
// KE: final — out = 2x + M_b*x + (gp*Wp)*pam_out + biasv. 128 blocks.
__global__ __launch_bounds__(256) void k_final(
    const void* __restrict__ x, const ushort* __restrict__ pam_part,
    const ushort* __restrict__ Wfull, const float* __restrict__ biasv,
    void* __restrict__ outv)
{
  __shared__ ushort u[64 * 128];
  __shared__ int sflag;
  int isbf = detect_isbf((const unsigned int*)x, &sflag);
  int blk = blockIdx.x;
  int nt = blk & 63, b = blk >> 6;
  int t = threadIdx.x;
  int n0 = nt * 64;
  int d = t >> 2, nl0 = (t & 3) * 16;
  size_t xbase = (size_t)(b * 64 + d) * 4096 + n0 + nl0;
#pragma unroll
  for (int i = 0; i < 16; ++i) {
    int nl = nl0 + i;
    int byte = (nl * 256 + d * 2) ^ ((nl & 7) << 4);
    *(ushort*)((char*)u + byte) = f2bf(loadf(x, xbase + i, isbf));
  }
  const ushort* pp = pam_part + (size_t)(b * 256 + d) * 4096 + n0 + nl0;
#pragma unroll
  for (int i = 0; i < 16; ++i) {
    float s = bf2f(pp[i]) + bf2f(pp[262144 + i]) + bf2f(pp[524288 + i]) + bf2f(pp[786432 + i]);
    int nl = nl0 + i;
    int byte = (nl * 256 + (64 + d) * 2) ^ ((nl & 7) << 4);
    *(ushort*)((char*)u + byte) = f2bf(s);
  }
  __syncthreads();

  int w = t >> 6, l = t & 63, l15 = l & 15, lh = l >> 4;
  f32x4 acc[4];
#pragma unroll
  for (int i = 0; i < 4; ++i) acc[i] = (f32x4){0.f, 0.f, 0.f, 0.f};
#pragma unroll
  for (int ks = 0; ks < 4; ++ks) {
    bf16x8 af = *(const bf16x8*)(Wfull + (size_t)(b * 64 + 16 * w + l15) * 128 + ks * 32 + lh * 8);
#pragma unroll
    for (int nt4 = 0; nt4 < 4; ++nt4) {
      int nl = nt4 * 16 + l15;
      int byte = (nl * 256 + (ks * 32 + lh * 8) * 2) ^ ((nl & 7) << 4);
      bf16x8 bfr = *(const bf16x8*)((const char*)u + byte);
      acc[nt4] = MFMA16(af, bfr, acc[nt4]);
    }
  }
#pragma unroll
  for (int nt4 = 0; nt4 < 4; ++nt4)
#pragma unroll
    for (int r = 0; r < 4; ++r) {
      int c = 16 * w + lh * 4 + r, nl = nt4 * 16 + l15;
      size_t xidx = (size_t)(b * 64 + c) * 4096 + n0 + nl;
      float xv = loadf(x, xidx, isbf);
      float v = acc[nt4][r] + 2.0f * xv + biasv[c];
      if (isbf) ((ushort*)outv)[xidx] = f2bf(v);
      else      ((float*)outv)[xidx]  = v;
    }
}

// ---------------------------------------------------------------------------
extern "C" void kernel_launch(void* const* d_in, const int* in_sizes, int n_in,
                              void* d_out, int out_size, void* d_ws, size_t ws_size,
                              hipStream_t stream) {
  const void* x   = d_in[0];
  const void* y   = d_in[1];
  const void* z   = d_in[2];
  const void* wq  = d_in[3];
  const void* bq  = d_in[4];
  const void* wk1 = d_in[5];
  const void* bk1 = d_in[6];
  const void* wk2 = d_in[7];
  const void* bk2 = d_in[8];
  const void* wk3 = d_in[9];
  const void* bk3 = d_in[10];
  const void* wv  = d_in[11];
  const void* bv  = d_in[12];
  const void* pwl = d_in[13];
  const void* pbl = d_in[14];
  const void* pg  = d_in[15];
  const void* cwl = d_in[16];
  const void* cbl = d_in[17];
  const void* cg  = d_in[18];

  char* ws = (char*)d_ws;
  ushort* QT      = (ushort*)(ws + 0);         //  512 KB  [2][4096][32] bf16
  ushort* KT      = (ushort*)(ws + 524288);    // 1536 KB  [6][4096][32] bf16
  ushort* Vp      = (ushort*)(ws + 2097152);   // 1024 KB  [2][64][4096] bf16 (sigma')
  float*  S_part  = (float*) (ws + 3145728);   //  384 KB  [4][2*3*4096] f32
  float*  e_part  = (float*) (ws + 3538944);   // 1536 KB  [2][3][16][64][64] f32
  ushort* pam_prt = (ushort*)(ws + 5111808);   // 4096 KB  [2][4][64][4096] bf16
  ushort* Wfull   = (ushort*)(ws + 9306112);   //   32 KB  [2][64][128] bf16
  float*  biasv   = (float*) (ws + 9338880);   //  256 B   [64] f32

  k_prep_all<<< 480, 256, 0, stream>>>(x, y, z, wq, bq, wk1, bk1, wk2, bk2, wk3, bk3,
                                       wv, bv, QT, KT, Vp, e_part);
  k_pass1   <<<1536, 256, 0, stream>>>(QT, KT, S_part);
  k_pam_out <<<2050, 256, 0, stream>>>(QT, KT, Vp, S_part, e_part, x,
                                       cwl, cbl, cg, pwl, pbl, pg, Wfull, biasv, pam_prt);
  k_final   <<< 128, 256, 0, stream>>>(x, pam_prt, Wfull, biasv, d_out);
}

// Round 8
// 133.543 us; speedup vs baseline: 1.0365x; 1.0209x over previous
//
#include <hip/hip_runtime.h>
#include <hip/hip_bf16.h>

// MsPAM+CAM fused, MI355X gfx950.  B=2, C=64, H=W=64, N=4096, Cq=8.
// 5-kernel pipeline. Softmax normalization folded into MFMA via spare Q/K
// slots (Q 8..13 = -log2(S) split pair, K one-hot 1.0), patched ONCE by a
// dedicated small kernel (k_patch). PAM pass2: P fully in registers; waves
// partition m; sigma' k-permutation makes the cross-half exchange a single
// v_permlane32_swap_b32; per-wave PV partials reduced across waves via LDS.

typedef __attribute__((ext_vector_type(8))) short bf16x8;
typedef __attribute__((ext_vector_type(4))) short s16x4;
typedef __attribute__((ext_vector_type(4))) float f32x4;

#define MFMA16(a, b, c) __builtin_amdgcn_mfma_f32_16x16x32_bf16(a, b, c, 0, 0, 0)
#define EX2(x) __builtin_amdgcn_exp2f(x)
#define LOG2E 1.4426950408889634f

__device__ __forceinline__ float bf2f(ushort u) {
  union { unsigned int i; float f; } v; v.i = ((unsigned int)u) << 16; return v.f;
}
__device__ __forceinline__ ushort f2bf(float f) {  // RNE
  union { float f; unsigned int i; } v; v.f = f;
  unsigned int r = v.i + 0x7FFFu + ((v.i >> 16) & 1u);
  return (ushort)(r >> 16);
}
__device__ __forceinline__ float loadf(const void* p, size_t i, int isbf) {
  return isbf ? bf2f(((const ushort*)p)[i]) : ((const float*)p)[i];
}
__device__ __forceinline__ bf16x8 load8(const void* p, size_t i, int isbf) {
  if (isbf) return *(const bf16x8*)((const ushort*)p + i);
  const float* f = (const float*)p + i;
  bf16x8 r;
#pragma unroll
  for (int j = 0; j < 8; ++j) r[j] = (short)f2bf(f[j]);
  return r;
}
__device__ __forceinline__ void loadf8(const void* p, size_t i, int isbf, float* o) {
  if (isbf) {
    bf16x8 v = *(const bf16x8*)((const ushort*)p + i);
#pragma unroll
    for (int j = 0; j < 8; ++j) o[j] = bf2f((ushort)v[j]);
  } else {
    const float* f = (const float*)p + i;
#pragma unroll
    for (int j = 0; j < 8; ++j) o[j] = f[j];
  }
}
// per-block dtype detect: bf16-packed x has low-16 exponent bits in [120,133].
__device__ __forceinline__ int detect_isbf(const unsigned int* xw, int* sflag) {
  int t = threadIdx.x;
  if (t < 64) {
    unsigned int w1 = xw[t], w2 = xw[64 + t];
    unsigned int e1 = (w1 >> 7) & 0xFFu, e2 = (w2 >> 7) & 0xFFu;
    unsigned long long b1 = __ballot(e1 >= 120u && e1 <= 133u);
    unsigned long long b2 = __ballot(e2 >= 120u && e2 <= 133u);
    if (t == 0) *sflag = (__popcll(b1) + __popcll(b2) > 64) ? 1 : 0;
  }
  __syncthreads();
  return *sflag;
}

// ---------------------------------------------------------------------------
// KA: fused prep. blocks 0..127: Q/K convs -> QT/KT; 128..383: Vp (sigma'-
//     permuted V conv); 384..479: CAM gram partials e_part.
__global__ __launch_bounds__(256) void k_prep_all(
    const void* __restrict__ x, const void* __restrict__ y, const void* __restrict__ z,
    const void* __restrict__ wq, const void* __restrict__ bq,
    const void* __restrict__ wk1, const void* __restrict__ bk1,
    const void* __restrict__ wk2, const void* __restrict__ bk2,
    const void* __restrict__ wk3, const void* __restrict__ bk3,
    const void* __restrict__ wv, const void* __restrict__ bv,
    ushort* __restrict__ QT, ushort* __restrict__ KT, ushort* __restrict__ Vp,
    float* __restrict__ e_part)
{
  __shared__ float wsh[4][8][64];
  __shared__ int sflag;
  int isbf = detect_isbf((const unsigned int*)x, &sflag);
  int blk = blockIdx.x, t = threadIdx.x;

  if (blk < 128) {
    // ---- Q/K1/K2/K3 convs, 4 threads per n (16 c each) + quad shfl reduce
    for (int i = t; i < 2048; i += 256) {
      int mat = i >> 9, rem = i & 511;
      const void* src = (mat == 0) ? wq : (mat == 1) ? wk1 : (mat == 2) ? wk2 : wk3;
      wsh[mat][rem >> 6][rem & 63] = loadf(src, rem, isbf);
    }
    __syncthreads();
    int gid = blk * 256 + t;            // 0..32767
    int qid = gid & 3;
    int n = (gid >> 2) & 4095;
    int b = gid >> 14;
    int c0 = qid * 16;
    float a[4][8];
#pragma unroll
    for (int m = 0; m < 4; ++m)
#pragma unroll
      for (int o = 0; o < 8; ++o) a[m][o] = 0.f;
    size_t base = (size_t)b * 262144 + n;
    for (int cc = 0; cc < 16; ++cc) {
      int c = c0 + cc;
      float xv = loadf(x, base + (size_t)c * 4096, isbf);
      float yv = loadf(y, base + (size_t)c * 4096, isbf);
      float zv = loadf(z, base + (size_t)c * 4096, isbf);
#pragma unroll
      for (int o = 0; o < 8; ++o) {
        a[0][o] += wsh[0][o][c] * xv;
        a[1][o] += wsh[1][o][c] * xv;
        a[2][o] += wsh[2][o][c] * yv;
        a[3][o] += wsh[3][o][c] * zv;
      }
    }
#pragma unroll
    for (int m = 0; m < 4; ++m)
#pragma unroll
      for (int o = 0; o < 8; ++o) {
        float v = a[m][o];
        v += __shfl_xor(v, 1, 64);
        v += __shfl_xor(v, 2, 64);
        a[m][o] = v;
      }
    int br = qid - 1;
    const void* bias = (qid == 0) ? bq : (qid == 1) ? bk1 : (qid == 2) ? bk2 : bk3;
    ushort* dst = (qid == 0) ? QT + (size_t)(b * 4096 + n) * 32
                             : KT + (size_t)((b * 3 + br) * 4096 + n) * 32;
    ushort row[32];
#pragma unroll
    for (int o = 0; o < 8; ++o) {
      float v = a[qid][o] + loadf(bias, o, isbf);
      row[o] = f2bf(qid == 0 ? LOG2E * v : v);
    }
#pragma unroll
    for (int o = 8; o < 32; ++o)
      row[o] = (qid > 0 && (o == 8 + 2 * br || o == 9 + 2 * br)) ? (ushort)0x3F80 : (ushort)0;
#pragma unroll
    for (int o = 0; o < 32; o += 2)
      *(unsigned int*)(dst + o) = (unsigned int)row[o] | ((unsigned int)row[o + 1] << 16);
  } else if (blk < 384) {
    // ---- Vp = sigma'-permuted (wv*x + bv). For each 32-m block, m-octet o
    //      lands at slots s1..s1+3 (lo quad) and s1+8..s1+11 (hi quad).
    int tid2 = (blk - 128) * 256 + t;   // 0..65535
    int b = tid2 >> 15, c = (tid2 >> 9) & 63, m0 = (tid2 & 511) * 8;
    float acc[8], xv[8];
    float bb = loadf(bv, c, isbf);
#pragma unroll
    for (int j = 0; j < 8; ++j) acc[j] = bb;
    size_t xb = (size_t)b * 262144 + m0;
    for (int d = 0; d < 64; ++d) {
      float w = loadf(wv, c * 64 + d, isbf);
      loadf8(x, xb + (size_t)d * 4096, isbf, xv);
#pragma unroll
      for (int j = 0; j < 8; ++j) acc[j] += w * xv[j];
    }
    int M5 = m0 & ~31;                   // 32-m block base
    int o = m0 & 31;                     // 0,8,16,24
    int s1 = (o & 16) | ((o & 8) >> 1);  // 0->0, 8->4, 16->16, 24->20
    s16x4 lo, hi;
#pragma unroll
    for (int j = 0; j < 4; ++j) { lo[j] = (short)f2bf(acc[j]); hi[j] = (short)f2bf(acc[4 + j]); }
    ushort* vb = Vp + (size_t)(b * 64 + c) * 4096 + M5;
    *(s16x4*)(vb + s1)     = lo;
    *(s16x4*)(vb + s1 + 8) = hi;
  } else {
    // ---- CAM gram partials e_part[b][k][ns16][64][64]
    int r2 = blk - 384;
    int ns = r2 & 15, r = r2 >> 4;      // r in 0..5
    int k = r % 3, b = r / 3;
    const void* A = x;
    const void* B = (k == 0) ? x : (k == 1) ? y : z;
    size_t boff = (size_t)b * 262144;
    int w = t >> 6, l = t & 63;
    int l15 = l & 15, lh = l >> 4;
    int cbase = 16 * w;
    f32x4 acc[4];
#pragma unroll
    for (int i = 0; i < 4; ++i) acc[i] = (f32x4){0.f, 0.f, 0.f, 0.f};
    int n0 = ns * 256;
    for (int step = 0; step < 8; ++step) {
      int nb = n0 + step * 32;
      bf16x8 af = load8(A, boff + (size_t)(cbase + l15) * 4096 + nb + lh * 8, isbf);
#pragma unroll
      for (int dt = 0; dt < 4; ++dt) {
        bf16x8 bfr = load8(B, boff + (size_t)(dt * 16 + l15) * 4096 + nb + lh * 8, isbf);
        acc[dt] = MFMA16(af, bfr, acc[dt]);
      }
    }
    float* out = e_part + (size_t)(((b * 3 + k) * 16 + ns) * 64) * 64;
#pragma unroll
    for (int dt = 0; dt < 4; ++dt)
#pragma unroll
      for (int rr = 0; rr < 4; ++rr) {
        int c = cbase + lh * 4 + rr, d = dt * 16 + l15;
        out[c * 64 + d] = acc[dt][rr];
      }
  }
}

// ---------------------------------------------------------------------------
// KB: PAM pass 1 — S_part[sl][(b*3+br)*4096+m] = sum_{n slice} exp2(Ehat). 1536 blocks.
__global__ __launch_bounds__(256) void k_pass1(
    const ushort* __restrict__ QT, const ushort* __restrict__ KT, float* __restrict__ S_part)
{
  int blk = blockIdx.x, t = threadIdx.x;
  int sl = blk & 3, mc = (blk >> 2) & 63, r3 = blk >> 8;  // r3 in 0..5
  int br = r3 % 3, b = r3 / 3;
  int w = t >> 6, l = t & 63;
  int l15 = l & 15, lh = l >> 4;
  int mbase = mc * 64 + w * 16;
  bf16x8 qf = *(const bf16x8*)(QT + (size_t)(b * 4096 + mbase + l15) * 32 + lh * 8);
  const ushort* Kb = KT + (size_t)((b * 3 + br) * 4096) * 32;
  float s = 0.f;
  int ns0 = sl * 64;
#pragma unroll 4
  for (int ns = ns0; ns < ns0 + 64; ++ns) {
    bf16x8 kf = *(const bf16x8*)(Kb + (size_t)(ns * 16 + l15) * 32 + lh * 8);
    f32x4 d = MFMA16(kf, qf, ((f32x4){0.f, 0.f, 0.f, 0.f}));
    s += EX2(d[0]) + EX2(d[1]) + EX2(d[2]) + EX2(d[3]);
  }
  s += __shfl_xor(s, 16, 64);
  s += __shfl_xor(s, 32, 64);
  if (l < 16) S_part[sl * 24576 + (b * 3 + br) * 4096 + mbase + l] = s;
}

// ---------------------------------------------------------------------------
// KC: blocks 0..95: ONE-TIME QT L-slot patch (coalesced, no redundancy);
//     blocks 96..97: CAM small (inline e_part reduce, softmax, Wfull, biasv).
__global__ __launch_bounds__(256) void k_patch(
    const float* __restrict__ S_part, ushort* __restrict__ QT,
    const float* __restrict__ e_part, const void* __restrict__ x,
    const void* __restrict__ cam_wl, const void* __restrict__ cam_bl, const void* __restrict__ cam_gamma,
    const void* __restrict__ pam_wl, const void* __restrict__ pam_bl, const void* __restrict__ pam_gamma,
    ushort* __restrict__ Wfull, float* __restrict__ biasv)
{
  int blk = blockIdx.x, t = threadIdx.x;
  if (blk < 96) {
    int i = blk * 256 + t;              // 24576
    float S = S_part[i] + S_part[24576 + i] + S_part[49152 + i] + S_part[73728 + i];
    float nL = -__builtin_amdgcn_logf(S);  // -log2(S)
    int m = i & 4095, b3br = i >> 12;
    int br = b3br % 3, b = b3br / 3;
    ushort c = f2bf(nL);
    ushort r = f2bf(nL - bf2f(c));
    ushort* qrow = QT + (size_t)(b * 4096 + m) * 32;
    qrow[8 + 2 * br] = c;
    qrow[9 + 2 * br] = r;
    return;
  }
  // ---------------- CAM small ----------------
  __shared__ float erow[64][65];
  __shared__ int sflag;
  int isbf = detect_isbf((const unsigned int*)x, &sflag);
  int b = blk - 96;
  int r = t >> 2, q = t & 3;
  float atot[16];
#pragma unroll
  for (int j = 0; j < 16; ++j) atot[j] = 0.f;
  for (int k = 0; k < 3; ++k) {
    const float* ep = e_part + (size_t)((b * 3 + k) * 16) * 4096;
    for (int i = t; i < 4096; i += 256) {
      float s = 0.f;
#pragma unroll
      for (int ks = 0; ks < 16; ++ks) s += ep[ks * 4096 + i];
      erow[i >> 6][i & 63] = s;
    }
    __syncthreads();
    float ev[16];
    float mn = 1e30f;
#pragma unroll
    for (int j = 0; j < 16; ++j) { ev[j] = erow[r][q * 16 + j]; mn = fminf(mn, ev[j]); }
    mn = fminf(mn, __shfl_xor(mn, 1, 64));
    mn = fminf(mn, __shfl_xor(mn, 2, 64));
    float s = 0.f;
#pragma unroll
    for (int j = 0; j < 16; ++j) { ev[j] = __expf(mn - ev[j]); s += ev[j]; }
    s += __shfl_xor(s, 1, 64);
    s += __shfl_xor(s, 2, 64);
    float inv = 1.0f / s;
#pragma unroll
    for (int j = 0; j < 16; ++j) atot[j] += ev[j] * inv;
    __syncthreads();
  }
#pragma unroll
  for (int j = 0; j < 16; ++j) erow[r][q * 16 + j] = atot[j];
  __syncthreads();
  float gc = loadf(cam_gamma, 0, isbf), gp = loadf(pam_gamma, 0, isbf);
  int c = t >> 2, d0 = (t & 3) * 16;
  float a[16];
#pragma unroll
  for (int i = 0; i < 16; ++i) a[i] = 0.f;
  for (int e = 0; e < 64; ++e) {
    float wv = loadf(cam_wl, c * 64 + e, isbf);
#pragma unroll
    for (int i = 0; i < 16; ++i) a[i] += wv * erow[e][d0 + i];
  }
#pragma unroll
  for (int i = 0; i < 16; ++i) {
    int d = d0 + i;
    Wfull[(size_t)(b * 64 + c) * 128 + d]      = f2bf(gc * a[i]);
    Wfull[(size_t)(b * 64 + c) * 128 + 64 + d] = f2bf(gp * loadf(pam_wl, c * 64 + d, isbf));
  }
  if (b == 0 && t < 64) biasv[t] = gp * loadf(pam_bl, t, isbf) + gc * loadf(cam_bl, t, isbf);
}

// ---------------------------------------------------------------------------
// KD: PAM pass 2 (pure). 2048 blocks = (b x 256 nt x 4 ms). Waves partition m:
//     per 128-m chunk each wave does E-MFMA(32m x 16n) -> EX2 -> cvt_pk ->
//     permlane32_swap -> 4 PV MFMA; cross-wave LDS reduce once at the end.
__global__ __launch_bounds__(256) void k_pam_out(
    const ushort* __restrict__ QT, const ushort* __restrict__ KT, const ushort* __restrict__ Vp,
    ushort* __restrict__ pam_part)
{
  __shared__ float red[4 * 64 * 17];
  int blk = blockIdx.x, t = threadIdx.x;
  int ms = blk & 3, nt = (blk >> 2) & 255, b = blk >> 10;
  int w = t >> 6, l = t & 63;
  int l15 = l & 15, lh = l >> 4;
  int n0 = nt * 16;

  bf16x8 kf[3];
#pragma unroll
  for (int br = 0; br < 3; ++br)
    kf[br] = *(const bf16x8*)(KT + (size_t)((b * 3 + br) * 4096 + n0 + l15) * 32 + lh * 8);

  f32x4 acc[4];
#pragma unroll
  for (int i = 0; i < 4; ++i) acc[i] = (f32x4){0.f, 0.f, 0.f, 0.f};
  const f32x4 Z = (f32x4){0.f, 0.f, 0.f, 0.f};
  const ushort* vrow = Vp + (size_t)(b * 64 + l15) * 4096;

  for (int ch = 0; ch < 8; ++ch) {
    int mbase = ms * 1024 + ch * 128 + 32 * w;    // wave-private 32-m slice
    const ushort* qb = QT + (size_t)(b * 4096 + mbase + l15) * 32 + lh * 8;
    bf16x8 qf0 = *(const bf16x8*)(qb);
    bf16x8 qf1 = *(const bf16x8*)(qb + 512);      // +16 rows
    f32x4 dA0 = MFMA16(qf0, kf[0], Z);
    f32x4 dA1 = MFMA16(qf0, kf[1], Z);
    f32x4 dA2 = MFMA16(qf0, kf[2], Z);
    f32x4 dB0 = MFMA16(qf1, kf[0], Z);
    f32x4 dB1 = MFMA16(qf1, kf[1], Z);
    f32x4 dB2 = MFMA16(qf1, kf[2], Z);
    float plo[4], phi[4];
#pragma unroll
    for (int rr = 0; rr < 4; ++rr) {
      plo[rr] = EX2(dA0[rr]) + EX2(dA1[rr]) + EX2(dA2[rr]);
      phi[rr] = EX2(dB0[rr]) + EX2(dB1[rr]) + EX2(dB2[rr]);
    }
    unsigned int a0, a1, b0, b1;
    asm("v_cvt_pk_bf16_f32 %0, %1, %2" : "=v"(a0) : "v"(plo[0]), "v"(plo[1]));
    asm("v_cvt_pk_bf16_f32 %0, %1, %2" : "=v"(a1) : "v"(plo[2]), "v"(plo[3]));
    asm("v_cvt_pk_bf16_f32 %0, %1, %2" : "=v"(b0) : "v"(phi[0]), "v"(phi[1]));
    asm("v_cvt_pk_bf16_f32 %0, %1, %2" : "=v"(b1) : "v"(phi[2]), "v"(phi[3]));
    asm("v_permlane32_swap_b32 %0, %1" : "+v"(a0), "+v"(b0));
    asm("v_permlane32_swap_b32 %0, %1" : "+v"(a1), "+v"(b1));
    union { unsigned int uw[4]; bf16x8 v; } pf;
    pf.uw[0] = a0; pf.uw[1] = a1; pf.uw[2] = b0; pf.uw[3] = b1;
#pragma unroll
    for (int ct = 0; ct < 4; ++ct) {
      bf16x8 vf = *(const bf16x8*)(vrow + (size_t)ct * 16 * 4096 + mbase + lh * 8);
      acc[ct] = MFMA16(vf, pf.v, acc[ct]);
    }
  }

  // cross-wave reduction: red[w][c][n], padded stride 17
#pragma unroll
  for (int ct = 0; ct < 4; ++ct)
#pragma unroll
    for (int rr = 0; rr < 4; ++rr)
      red[w * 1088 + (ct * 16 + lh * 4 + rr) * 17 + l15] = acc[ct][rr];
  __syncthreads();
  {
    int c = t >> 2, nb = (t & 3) * 4;
    float s0 = red[c * 17 + nb + 0] + red[1088 + c * 17 + nb + 0] + red[2176 + c * 17 + nb + 0] + red[3264 + c * 17 + nb + 0];
    float s1 = red[c * 17 + nb + 1] + red[1088 + c * 17 + nb + 1] + red[2176 + c * 17 + nb + 1] + red[3264 + c * 17 + nb + 1];
    float s2 = red[c * 17 + nb + 2] + red[1088 + c * 17 + nb + 2] + red[2176 + c * 17 + nb + 2] + red[3264 + c * 17 + nb + 2];
    float s3 = red[c * 17 + nb + 3] + red[1088 + c * 17 + nb + 3] + red[2176 + c * 17 + nb + 3] + red[3264 + c * 17 + nb + 3];
    uint2 o;
    asm("v_cvt_pk_bf16_f32 %0, %1, %2" : "=v"(o.x) : "v"(s0), "v"(s1));
    asm("v_cvt_pk_bf16_f32 %0, %1, %2" : "=v"(o.y) : "v"(s2), "v"(s3));
    *(uint2*)(pam_part + (size_t)((b * 4 + ms) * 64 + c) * 4096 + n0 + nb) = o;
  }
}

// ---------------------------------------------------------------------------
// KE: final — out = 2x + M_b*x + (gp*Wp)*pam_out + biasv. 128 blocks.
__global__ __launch_bounds__(256) void k_final(
    const void* __restrict__ x, const ushort* __restrict__ pam_part,
    const ushort* __restrict__ Wfull, const float* __restrict__ biasv,
    void* __restrict__ outv)
{
  __shared__ ushort u[64 * 128];
  __shared__ int sflag;
  int isbf = detect_isbf((const unsigned int*)x, &sflag);
  int blk = blockIdx.x;
  int nt = blk & 63, b = blk >> 6;
  int t = threadIdx.x;
  int n0 = nt * 64;
  int d = t >> 2, nl0 = (t & 3) * 16;
  size_t xbase = (size_t)(b * 64 + d) * 4096 + n0 + nl0;
#pragma unroll
  for (int i = 0; i < 16; ++i) {
    int nl = nl0 + i;
    int byte = (nl * 256 + d * 2) ^ ((nl & 7) << 4);
    *(ushort*)((char*)u + byte) = f2bf(loadf(x, xbase + i, isbf));
  }
  const ushort* pp = pam_part + (size_t)(b * 256 + d) * 4096 + n0 + nl0;
#pragma unroll
  for (int i = 0; i < 16; ++i) {
    float s = bf2f(pp[i]) + bf2f(pp[262144 + i]) + bf2f(pp[524288 + i]) + bf2f(pp[786432 + i]);
    int nl = nl0 + i;
    int byte = (nl * 256 + (64 + d) * 2) ^ ((nl & 7) << 4);
    *(ushort*)((char*)u + byte) = f2bf(s);
  }
  __syncthreads();

  int w = t >> 6, l = t & 63, l15 = l & 15, lh = l >> 4;
  f32x4 acc[4];
#pragma unroll
  for (int i = 0; i < 4; ++i) acc[i] = (f32x4){0.f, 0.f, 0.f, 0.f};
#pragma unroll
  for (int ks = 0; ks < 4; ++ks) {
    bf16x8 af = *(const bf16x8*)(Wfull + (size_t)(b * 64 + 16 * w + l15) * 128 + ks * 32 + lh * 8);
#pragma unroll
    for (int nt4 = 0; nt4 < 4; ++nt4) {
      int nl = nt4 * 16 + l15;
      int byte = (nl * 256 + (ks * 32 + lh * 8) * 2) ^ ((nl & 7) << 4);
      bf16x8 bfr = *(const bf16x8*)((const char*)u + byte);
      acc[nt4] = MFMA16(af, bfr, acc[nt4]);
    }
  }
#pragma unroll
  for (int nt4 = 0; nt4 < 4; ++nt4)
#pragma unroll
    for (int r = 0; r < 4; ++r) {
      int c = 16 * w + lh * 4 + r, nl = nt4 * 16 + l15;
      size_t xidx = (size_t)(b * 64 + c) * 4096 + n0 + nl;
      float xv = loadf(x, xidx, isbf);
      float v = acc[nt4][r] + 2.0f * xv + biasv[c];
      if (isbf) ((ushort*)outv)[xidx] = f2bf(v);
      else      ((float*)outv)[xidx]  = v;
    }
}

// ---------------------------------------------------------------------------
extern "C" void kernel_launch(void* const* d_in, const int* in_sizes, int n_in,
                              void* d_out, int out_size, void* d_ws, size_t ws_size,
                              hipStream_t stream) {
  const void* x   = d_in[0];
  const void* y   = d_in[1];
  const void* z   = d_in[2];
  const void* wq  = d_in[3];
  const void* bq  = d_in[4];
  const void* wk1 = d_in[5];
  const void* bk1 = d_in[6];
  const void* wk2 = d_in[7];
  const void* bk2 = d_in[8];
  const void* wk3 = d_in[9];
  const void* bk3 = d_in[10];
  const void* wv  = d_in[11];
  const void* bv  = d_in[12];
  const void* pwl = d_in[13];
  const void* pbl = d_in[14];
  const void* pg  = d_in[15];
  const void* cwl = d_in[16];
  const void* cbl = d_in[17];
  const void* cg  = d_in[18];

  char* ws = (char*)d_ws;
  ushort* QT      = (ushort*)(ws + 0);         //  512 KB  [2][4096][32] bf16
  ushort* KT      = (ushort*)(ws + 524288);    // 1536 KB  [6][4096][32] bf16
  ushort* Vp      = (ushort*)(ws + 2097152);   // 1024 KB  [2][64][4096] bf16 (sigma')
  float*  S_part  = (float*) (ws + 3145728);   //  384 KB  [4][2*3*4096] f32
  float*  e_part  = (float*) (ws + 3538944);   // 1536 KB  [2][3][16][64][64] f32
  ushort* pam_prt = (ushort*)(ws + 5111808);   // 4096 KB  [2][4][64][4096] bf16
  ushort* Wfull   = (ushort*)(ws + 9306112);   //   32 KB  [2][64][128] bf16
  float*  biasv   = (float*) (ws + 9338880);   //  256 B   [64] f32

  k_prep_all<<< 480, 256, 0, stream>>>(x, y, z, wq, bq, wk1, bk1, wk2, bk2, wk3, bk3,
                                       wv, bv, QT, KT, Vp, e_part);
  k_pass1   <<<1536, 256, 0, stream>>>(QT, KT, S_part);
  k_patch   <<<  98, 256, 0, stream>>>(S_part, QT, e_part, x, cwl, cbl, cg, pwl, pbl, pg,
                                       Wfull, biasv);
  k_pam_out <<<2048, 256, 0, stream>>>(QT, KT, Vp, pam_prt);
  k_final   <<< 128, 256, 0, stream>>>(x, pam_prt, Wfull, biasv, d_out);
}

// Round 9
// 98.304 us; speedup vs baseline: 1.4081x; 1.3585x over previous
//
#include <hip/hip_runtime.h>
#include <hip/hip_bf16.h>

// MsPAM+CAM fused, MI355X gfx950.  B=2, C=64, H=W=64, N=4096, Cq=8.
// 5-kernel pipeline. Softmax normalization folded into MFMA via spare Q/K
// slots (Q 8..13 = -log2(S) split pair, K one-hot 1.0), patched once.
// PAM pass2: P in registers (bit_cast, NO union->scratch), n-tile 32, waves
// partition m, permlane32_swap cross-half exchange, one LDS reduce at end.

typedef __attribute__((ext_vector_type(8))) short bf16x8;
typedef __attribute__((ext_vector_type(4))) short s16x4;
typedef __attribute__((ext_vector_type(4))) float f32x4;
typedef __attribute__((ext_vector_type(4))) unsigned int u32x4;

#define MFMA16(a, b, c) __builtin_amdgcn_mfma_f32_16x16x32_bf16(a, b, c, 0, 0, 0)
#define EX2(x) __builtin_amdgcn_exp2f(x)
#define LOG2E 1.4426950408889634f

__device__ __forceinline__ float bf2f(ushort u) {
  union { unsigned int i; float f; } v; v.i = ((unsigned int)u) << 16; return v.f;
}
__device__ __forceinline__ ushort f2bf(float f) {  // RNE
  union { float f; unsigned int i; } v; v.f = f;
  unsigned int r = v.i + 0x7FFFu + ((v.i >> 16) & 1u);
  return (ushort)(r >> 16);
}
__device__ __forceinline__ float loadf(const void* p, size_t i, int isbf) {
  return isbf ? bf2f(((const ushort*)p)[i]) : ((const float*)p)[i];
}
__device__ __forceinline__ bf16x8 load8(const void* p, size_t i, int isbf) {
  if (isbf) return *(const bf16x8*)((const ushort*)p + i);
  const float* f = (const float*)p + i;
  bf16x8 r;
#pragma unroll
  for (int j = 0; j < 8; ++j) r[j] = (short)f2bf(f[j]);
  return r;
}
__device__ __forceinline__ void loadf8(const void* p, size_t i, int isbf, float* o) {
  if (isbf) {
    bf16x8 v = *(const bf16x8*)((const ushort*)p + i);
#pragma unroll
    for (int j = 0; j < 8; ++j) o[j] = bf2f((ushort)v[j]);
  } else {
    const float* f = (const float*)p + i;
#pragma unroll
    for (int j = 0; j < 8; ++j) o[j] = f[j];
  }
}
// per-block dtype detect: bf16-packed x has low-16 exponent bits in [120,133].
__device__ __forceinline__ int detect_isbf(const unsigned int* xw, int* sflag) {
  int t = threadIdx.x;
  if (t < 64) {
    unsigned int w1 = xw[t], w2 = xw[64 + t];
    unsigned int e1 = (w1 >> 7) & 0xFFu, e2 = (w2 >> 7) & 0xFFu;
    unsigned long long b1 = __ballot(e1 >= 120u && e1 <= 133u);
    unsigned long long b2 = __ballot(e2 >= 120u && e2 <= 133u);
    if (t == 0) *sflag = (__popcll(b1) + __popcll(b2) > 64) ? 1 : 0;
  }
  __syncthreads();
  return *sflag;
}

// ---------------------------------------------------------------------------
// KA: fused prep. blocks 0..127: Q/K convs -> QT/KT; 128..383: Vp (sigma'-
//     permuted V conv); 384..479: CAM gram partials e_part.
__global__ __launch_bounds__(256) void k_prep_all(
    const void* __restrict__ x, const void* __restrict__ y, const void* __restrict__ z,
    const void* __restrict__ wq, const void* __restrict__ bq,
    const void* __restrict__ wk1, const void* __restrict__ bk1,
    const void* __restrict__ wk2, const void* __restrict__ bk2,
    const void* __restrict__ wk3, const void* __restrict__ bk3,
    const void* __restrict__ wv, const void* __restrict__ bv,
    ushort* __restrict__ QT, ushort* __restrict__ KT, ushort* __restrict__ Vp,
    float* __restrict__ e_part)
{
  __shared__ float wsh[4][8][64];
  __shared__ int sflag;
  int isbf = detect_isbf((const unsigned int*)x, &sflag);
  int blk = blockIdx.x, t = threadIdx.x;

  if (blk < 128) {
    for (int i = t; i < 2048; i += 256) {
      int mat = i >> 9, rem = i & 511;
      const void* src = (mat == 0) ? wq : (mat == 1) ? wk1 : (mat == 2) ? wk2 : wk3;
      wsh[mat][rem >> 6][rem & 63] = loadf(src, rem, isbf);
    }
    __syncthreads();
    int gid = blk * 256 + t;            // 0..32767
    int qid = gid & 3;
    int n = (gid >> 2) & 4095;
    int b = gid >> 14;
    int c0 = qid * 16;
    float a[4][8];
#pragma unroll
    for (int m = 0; m < 4; ++m)
#pragma unroll
      for (int o = 0; o < 8; ++o) a[m][o] = 0.f;
    size_t base = (size_t)b * 262144 + n;
    for (int cc = 0; cc < 16; ++cc) {
      int c = c0 + cc;
      float xv = loadf(x, base + (size_t)c * 4096, isbf);
      float yv = loadf(y, base + (size_t)c * 4096, isbf);
      float zv = loadf(z, base + (size_t)c * 4096, isbf);
#pragma unroll
      for (int o = 0; o < 8; ++o) {
        a[0][o] += wsh[0][o][c] * xv;
        a[1][o] += wsh[1][o][c] * xv;
        a[2][o] += wsh[2][o][c] * yv;
        a[3][o] += wsh[3][o][c] * zv;
      }
    }
#pragma unroll
    for (int m = 0; m < 4; ++m)
#pragma unroll
      for (int o = 0; o < 8; ++o) {
        float v = a[m][o];
        v += __shfl_xor(v, 1, 64);
        v += __shfl_xor(v, 2, 64);
        a[m][o] = v;
      }
    int br = qid - 1;
    const void* bias = (qid == 0) ? bq : (qid == 1) ? bk1 : (qid == 2) ? bk2 : bk3;
    ushort* dst = (qid == 0) ? QT + (size_t)(b * 4096 + n) * 32
                             : KT + (size_t)((b * 3 + br) * 4096 + n) * 32;
    ushort row[32];
#pragma unroll
    for (int o = 0; o < 8; ++o) {
      float v = a[qid][o] + loadf(bias, o, isbf);
      row[o] = f2bf(qid == 0 ? LOG2E * v : v);
    }
#pragma unroll
    for (int o = 8; o < 32; ++o)
      row[o] = (qid > 0 && (o == 8 + 2 * br || o == 9 + 2 * br)) ? (ushort)0x3F80 : (ushort)0;
#pragma unroll
    for (int o = 0; o < 32; o += 2)
      *(unsigned int*)(dst + o) = (unsigned int)row[o] | ((unsigned int)row[o + 1] << 16);
  } else if (blk < 384) {
    // ---- Vp = sigma'-permuted (wv*x + bv): octet o -> slots s1..s1+3, s1+8..s1+11
    int tid2 = (blk - 128) * 256 + t;   // 0..65535
    int b = tid2 >> 15, c = (tid2 >> 9) & 63, m0 = (tid2 & 511) * 8;
    float acc[8], xv[8];
    float bb = loadf(bv, c, isbf);
#pragma unroll
    for (int j = 0; j < 8; ++j) acc[j] = bb;
    size_t xb = (size_t)b * 262144 + m0;
    for (int d = 0; d < 64; ++d) {
      float w = loadf(wv, c * 64 + d, isbf);
      loadf8(x, xb + (size_t)d * 4096, isbf, xv);
#pragma unroll
      for (int j = 0; j < 8; ++j) acc[j] += w * xv[j];
    }
    int M5 = m0 & ~31;
    int o = m0 & 31;                     // 0,8,16,24
    int s1 = (o & 16) | ((o & 8) >> 1);  // 0->0, 8->4, 16->16, 24->20
    s16x4 lo, hi;
#pragma unroll
    for (int j = 0; j < 4; ++j) { lo[j] = (short)f2bf(acc[j]); hi[j] = (short)f2bf(acc[4 + j]); }
    ushort* vb = Vp + (size_t)(b * 64 + c) * 4096 + M5;
    *(s16x4*)(vb + s1)     = lo;
    *(s16x4*)(vb + s1 + 8) = hi;
  } else {
    // ---- CAM gram partials e_part[b][k][ns16][64][64]
    int r2 = blk - 384;
    int ns = r2 & 15, r = r2 >> 4;      // r in 0..5
    int k = r % 3, b = r / 3;
    const void* A = x;
    const void* B = (k == 0) ? x : (k == 1) ? y : z;
    size_t boff = (size_t)b * 262144;
    int w = t >> 6, l = t & 63;
    int l15 = l & 15, lh = l >> 4;
    int cbase = 16 * w;
    f32x4 acc[4];
#pragma unroll
    for (int i = 0; i < 4; ++i) acc[i] = (f32x4){0.f, 0.f, 0.f, 0.f};
    int n0 = ns * 256;
    for (int step = 0; step < 8; ++step) {
      int nb = n0 + step * 32;
      bf16x8 af = load8(A, boff + (size_t)(cbase + l15) * 4096 + nb + lh * 8, isbf);
#pragma unroll
      for (int dt = 0; dt < 4; ++dt) {
        bf16x8 bfr = load8(B, boff + (size_t)(dt * 16 + l15) * 4096 + nb + lh * 8, isbf);
        acc[dt] = MFMA16(af, bfr, acc[dt]);
      }
    }
    float* out = e_part + (size_t)(((b * 3 + k) * 16 + ns) * 64) * 64;
#pragma unroll
    for (int dt = 0; dt < 4; ++dt)
#pragma unroll
      for (int rr = 0; rr < 4; ++rr) {
        int c = cbase + lh * 4 + rr, d = dt * 16 + l15;
        out[c * 64 + d] = acc[dt][rr];
      }
  }
}

// ---------------------------------------------------------------------------
// KB: blocks 0..1535: PAM pass 1 S_part; 1536..1631: reduce e_part -> e_red.
__global__ __launch_bounds__(256) void k_pass1(
    const ushort* __restrict__ QT, const ushort* __restrict__ KT,
    const float* __restrict__ e_part, float* __restrict__ S_part, float* __restrict__ e_red)
{
  int blk = blockIdx.x, t = threadIdx.x;
  if (blk < 1536) {
    int sl = blk & 3, mc = (blk >> 2) & 63, r3 = blk >> 8;  // r3 in 0..5
    int br = r3 % 3, b = r3 / 3;
    int w = t >> 6, l = t & 63;
    int l15 = l & 15, lh = l >> 4;
    int mbase = mc * 64 + w * 16;
    bf16x8 qf = *(const bf16x8*)(QT + (size_t)(b * 4096 + mbase + l15) * 32 + lh * 8);
    const ushort* Kb = KT + (size_t)((b * 3 + br) * 4096) * 32;
    float s = 0.f;
    int ns0 = sl * 64;
#pragma unroll 4
    for (int ns = ns0; ns < ns0 + 64; ++ns) {
      bf16x8 kf = *(const bf16x8*)(Kb + (size_t)(ns * 16 + l15) * 32 + lh * 8);
      f32x4 d = MFMA16(kf, qf, ((f32x4){0.f, 0.f, 0.f, 0.f}));
      s += EX2(d[0]) + EX2(d[1]) + EX2(d[2]) + EX2(d[3]);
    }
    s += __shfl_xor(s, 16, 64);
    s += __shfl_xor(s, 32, 64);
    if (l < 16) S_part[sl * 24576 + (b * 3 + br) * 4096 + mbase + l] = s;
  } else {
    int i = (blk - 1536) * 256 + t;     // 24576
    const float* p = e_part + (size_t)(i >> 12) * 65536 + (i & 4095);
    float s = 0.f;
#pragma unroll
    for (int ks = 0; ks < 16; ++ks) s += p[ks * 4096];
    e_red[i] = s;
  }
}

// ---------------------------------------------------------------------------
// KC: blocks 0..95: ONE-TIME QT L-slot patch; 96..97: CAM small (reads e_red).
__global__ __launch_bounds__(256) void k_patch(
    const float* __restrict__ S_part, ushort* __restrict__ QT,
    const float* __restrict__ e_red, const void* __restrict__ x,
    const void* __restrict__ cam_wl, const void* __restrict__ cam_bl, const void* __restrict__ cam_gamma,
    const void* __restrict__ pam_wl, const void* __restrict__ pam_bl, const void* __restrict__ pam_gamma,
    ushort* __restrict__ Wfull, float* __restrict__ biasv)
{
  int blk = blockIdx.x, t = threadIdx.x;
  if (blk < 96) {
    int i = blk * 256 + t;              // 24576
    float S = S_part[i] + S_part[24576 + i] + S_part[49152 + i] + S_part[73728 + i];
    float nL = -__builtin_amdgcn_logf(S);  // -log2(S)
    int m = i & 4095, b3br = i >> 12;
    int br = b3br % 3, b = b3br / 3;
    ushort c = f2bf(nL);
    ushort r = f2bf(nL - bf2f(c));
    ushort* qrow = QT + (size_t)(b * 4096 + m) * 32;
    qrow[8 + 2 * br] = c;
    qrow[9 + 2 * br] = r;
    return;
  }
  // ---------------- CAM small ----------------
  __shared__ float erow[64][65];
  __shared__ int sflag;
  int isbf = detect_isbf((const unsigned int*)x, &sflag);
  int b = blk - 96;
  int r = t >> 2, q = t & 3;
  float atot[16];
#pragma unroll
  for (int j = 0; j < 16; ++j) atot[j] = 0.f;
  for (int k = 0; k < 3; ++k) {
    const float* ep = e_red + (size_t)(b * 3 + k) * 4096;
    for (int i = t; i < 4096; i += 256) erow[i >> 6][i & 63] = ep[i];
    __syncthreads();
    float ev[16];
    float mn = 1e30f;
#pragma unroll
    for (int j = 0; j < 16; ++j) { ev[j] = erow[r][q * 16 + j]; mn = fminf(mn, ev[j]); }
    mn = fminf(mn, __shfl_xor(mn, 1, 64));
    mn = fminf(mn, __shfl_xor(mn, 2, 64));
    float s = 0.f;
#pragma unroll
    for (int j = 0; j < 16; ++j) { ev[j] = __expf(mn - ev[j]); s += ev[j]; }
    s += __shfl_xor(s, 1, 64);
    s += __shfl_xor(s, 2, 64);
    float inv = 1.0f / s;
#pragma unroll
    for (int j = 0; j < 16; ++j) atot[j] += ev[j] * inv;
    __syncthreads();
  }
#pragma unroll
  for (int j = 0; j < 16; ++j) erow[r][q * 16 + j] = atot[j];
  __syncthreads();
  float gc = loadf(cam_gamma, 0, isbf), gp = loadf(pam_gamma, 0, isbf);
  int c = t >> 2, d0 = (t & 3) * 16;
  float a[16];
#pragma unroll
  for (int i = 0; i < 16; ++i) a[i] = 0.f;
  for (int e = 0; e < 64; ++e) {
    float wv = loadf(cam_wl, c * 64 + e, isbf);
#pragma unroll
    for (int i = 0; i < 16; ++i) a[i] += wv * erow[e][d0 + i];
  }
#pragma unroll
  for (int i = 0; i < 16; ++i) {
    int d = d0 + i;
    Wfull[(size_t)(b * 64 + c) * 128 + d]      = f2bf(gc * a[i]);
    Wfull[(size_t)(b * 64 + c) * 128 + 64 + d] = f2bf(gp * loadf(pam_wl, c * 64 + d, isbf));
  }
  if (b == 0 && t < 64) biasv[t] = gp * loadf(pam_bl, t, isbf) + gc * loadf(cam_bl, t, isbf);
}

// ---------------------------------------------------------------------------
// KD: PAM pass 2 (pure). 1024 blocks = (b x 128 nt32 x 4 ms). Waves partition m:
//     per 128-m chunk each wave: 2x(6 E-MFMA -> 24 EX2 -> cvt_pk ->
//     permlane32_swap -> bit_cast -> 4 PV MFMA); V loads shared across n16.
//     Cross-wave LDS reduce once at the end. NO union (register-only pf).
__global__ __launch_bounds__(256) void k_pam_out(
    const ushort* __restrict__ QT, const ushort* __restrict__ KT, const ushort* __restrict__ Vp,
    ushort* __restrict__ pam_part)
{
  __shared__ float red[4 * 64 * 33];   // 33792 B
  int blk = blockIdx.x, t = threadIdx.x;
  int ms = blk & 3, nt = (blk >> 2) & 127, b = blk >> 9;
  int w = t >> 6, l = t & 63;
  int l15 = l & 15, lh = l >> 4;
  int n0 = nt * 32;

  bf16x8 kf[3][2];
#pragma unroll
  for (int br = 0; br < 3; ++br)
#pragma unroll
    for (int n16 = 0; n16 < 2; ++n16)
      kf[br][n16] = *(const bf16x8*)(KT + (size_t)((b * 3 + br) * 4096 + n0 + n16 * 16 + l15) * 32 + lh * 8);

  f32x4 acc[4][2];
#pragma unroll
  for (int i = 0; i < 4; ++i)
#pragma unroll
    for (int j = 0; j < 2; ++j) acc[i][j] = (f32x4){0.f, 0.f, 0.f, 0.f};
  const f32x4 Z = (f32x4){0.f, 0.f, 0.f, 0.f};
  const ushort* vrow = Vp + (size_t)(b * 64 + l15) * 4096;

  for (int ch = 0; ch < 8; ++ch) {
    int mbase = ms * 1024 + ch * 128 + 32 * w;    // wave-private 32-m slice
    const ushort* qb = QT + (size_t)(b * 4096 + mbase + l15) * 32 + lh * 8;
    bf16x8 qf0 = *(const bf16x8*)(qb);
    bf16x8 qf1 = *(const bf16x8*)(qb + 512);      // +16 rows
    bf16x8 vf0 = *(const bf16x8*)(vrow + 0 * 65536 + mbase + lh * 8);
    bf16x8 vf1 = *(const bf16x8*)(vrow + 1 * 65536 + mbase + lh * 8);
    bf16x8 vf2 = *(const bf16x8*)(vrow + 2 * 65536 + mbase + lh * 8);
    bf16x8 vf3 = *(const bf16x8*)(vrow + 3 * 65536 + mbase + lh * 8);
#pragma unroll
    for (int n16 = 0; n16 < 2; ++n16) {
      f32x4 dA0 = MFMA16(qf0, kf[0][n16], Z);
      f32x4 dA1 = MFMA16(qf0, kf[1][n16], Z);
      f32x4 dA2 = MFMA16(qf0, kf[2][n16], Z);
      f32x4 dB0 = MFMA16(qf1, kf[0][n16], Z);
      f32x4 dB1 = MFMA16(qf1, kf[1][n16], Z);
      f32x4 dB2 = MFMA16(qf1, kf[2][n16], Z);
      float plo[4], phi[4];
#pragma unroll
      for (int rr = 0; rr < 4; ++rr) {
        plo[rr] = EX2(dA0[rr]) + EX2(dA1[rr]) + EX2(dA2[rr]);
        phi[rr] = EX2(dB0[rr]) + EX2(dB1[rr]) + EX2(dB2[rr]);
      }
      unsigned int a0, a1, b0, b1;
      asm("v_cvt_pk_bf16_f32 %0, %1, %2" : "=v"(a0) : "v"(plo[0]), "v"(plo[1]));
      asm("v_cvt_pk_bf16_f32 %0, %1, %2" : "=v"(a1) : "v"(plo[2]), "v"(plo[3]));
      asm("v_cvt_pk_bf16_f32 %0, %1, %2" : "=v"(b0) : "v"(phi[0]), "v"(phi[1]));
      asm("v_cvt_pk_bf16_f32 %0, %1, %2" : "=v"(b1) : "v"(phi[2]), "v"(phi[3]));
      asm("v_permlane32_swap_b32 %0, %1" : "+v"(a0), "+v"(b0));
      asm("v_permlane32_swap_b32 %0, %1" : "+v"(a1), "+v"(b1));
      u32x4 wv;
      wv[0] = a0; wv[1] = a1; wv[2] = b0; wv[3] = b1;
      bf16x8 pf = __builtin_bit_cast(bf16x8, wv);   // registers only
      acc[0][n16] = MFMA16(vf0, pf, acc[0][n16]);
      acc[1][n16] = MFMA16(vf1, pf, acc[1][n16]);
      acc[2][n16] = MFMA16(vf2, pf, acc[2][n16]);
      acc[3][n16] = MFMA16(vf3, pf, acc[3][n16]);
    }
  }

  // cross-wave reduction: red[w][c][32n], padded stride 33
#pragma unroll
  for (int ct = 0; ct < 4; ++ct)
#pragma unroll
    for (int n16 = 0; n16 < 2; ++n16)
#pragma unroll
      for (int rr = 0; rr < 4; ++rr)
        red[w * 2112 + (ct * 16 + lh * 4 + rr) * 33 + n16 * 16 + l15] = acc[ct][n16][rr];
  __syncthreads();
  {
    int c = t >> 2, nb = (t & 3) * 8;
    float s[8];
#pragma unroll
    for (int j = 0; j < 8; ++j) {
      int o = c * 33 + nb + j;
      s[j] = red[o] + red[2112 + o] + red[4224 + o] + red[6336 + o];
    }
    unsigned int o0, o1, o2, o3;
    asm("v_cvt_pk_bf16_f32 %0, %1, %2" : "=v"(o0) : "v"(s[0]), "v"(s[1]));
    asm("v_cvt_pk_bf16_f32 %0, %1, %2" : "=v"(o1) : "v"(s[2]), "v"(s[3]));
    asm("v_cvt_pk_bf16_f32 %0, %1, %2" : "=v"(o2) : "v"(s[4]), "v"(s[5]));
    asm("v_cvt_pk_bf16_f32 %0, %1, %2" : "=v"(o3) : "v"(s[6]), "v"(s[7]));
    u32x4 ov;
    ov[0] = o0; ov[1] = o1; ov[2] = o2; ov[3] = o3;
    *(u32x4*)(pam_part + (size_t)((b * 4 + ms) * 64 + c) * 4096 + n0 + nb) = ov;
  }
}

// ---------------------------------------------------------------------------
// KE: final — out = 2x + M_b*x + (gp*Wp)*pam_out + biasv. 128 blocks.
__global__ __launch_bounds__(256) void k_final(
    const void* __restrict__ x, const ushort* __restrict__ pam_part,
    const ushort* __restrict__ Wfull, const float* __restrict__ biasv,
    void* __restrict__ outv)
{
  __shared__ ushort u[64 * 128];
  __shared__ int sflag;
  int isbf = detect_isbf((const unsigned int*)x, &sflag);
  int blk = blockIdx.x;
  int nt = blk & 63, b = blk >> 6;
  int t = threadIdx.x;
  int n0 = nt * 64;
  int d = t >> 2, nl0 = (t & 3) * 16;
  size_t xbase = (size_t)(b * 64 + d) * 4096 + n0 + nl0;
#pragma unroll
  for (int i = 0; i < 16; ++i) {
    int nl = nl0 + i;
    int byte = (nl * 256 + d * 2) ^ ((nl & 7) << 4);
    *(ushort*)((char*)u + byte) = f2bf(loadf(x, xbase + i, isbf));
  }
  const ushort* pp = pam_part + (size_t)(b * 256 + d) * 4096 + n0 + nl0;
#pragma unroll
  for (int i = 0; i < 16; ++i) {
    float s = bf2f(pp[i]) + bf2f(pp[262144 + i]) + bf2f(pp[524288 + i]) + bf2f(pp[786432 + i]);
    int nl = nl0 + i;
    int byte = (nl * 256 + (64 + d) * 2) ^ ((nl & 7) << 4);
    *(ushort*)((char*)u + byte) = f2bf(s);
  }
  __syncthreads();

  int w = t >> 6, l = t & 63, l15 = l & 15, lh = l >> 4;
  f32x4 acc[4];
#pragma unroll
  for (int i = 0; i < 4; ++i) acc[i] = (f32x4){0.f, 0.f, 0.f, 0.f};
#pragma unroll
  for (int ks = 0; ks < 4; ++ks) {
    bf16x8 af = *(const bf16x8*)(Wfull + (size_t)(b * 64 + 16 * w + l15) * 128 + ks * 32 + lh * 8);
#pragma unroll
    for (int nt4 = 0; nt4 < 4; ++nt4) {
      int nl = nt4 * 16 + l15;
      int byte = (nl * 256 + (ks * 32 + lh * 8) * 2) ^ ((nl & 7) << 4);
      bf16x8 bfr = *(const bf16x8*)((const char*)u + byte);
      acc[nt4] = MFMA16(af, bfr, acc[nt4]);
    }
  }
#pragma unroll
  for (int nt4 = 0; nt4 < 4; ++nt4)
#pragma unroll
    for (int r = 0; r < 4; ++r) {
      int c = 16 * w + lh * 4 + r, nl = nt4 * 16 + l15;
      size_t xidx = (size_t)(b * 64 + c) * 4096 + n0 + nl;
      float xv = loadf(x, xidx, isbf);
      float v = acc[nt4][r] + 2.0f * xv + biasv[c];
      if (isbf) ((ushort*)outv)[xidx] = f2bf(v);
      else      ((float*)outv)[xidx]  = v;
    }
}

// ---------------------------------------------------------------------------
extern "C" void kernel_launch(void* const* d_in, const int* in_sizes, int n_in,
                              void* d_out, int out_size, void* d_ws, size_t ws_size,
                              hipStream_t stream) {
  const void* x   = d_in[0];
  const void* y   = d_in[1];
  const void* z   = d_in[2];
  const void* wq  = d_in[3];
  const void* bq  = d_in[4];
  const void* wk1 = d_in[5];
  const void* bk1 = d_in[6];
  const void* wk2 = d_in[7];
  const void* bk2 = d_in[8];
  const void* wk3 = d_in[9];
  const void* bk3 = d_in[10];
  const void* wv  = d_in[11];
  const void* bv  = d_in[12];
  const void* pwl = d_in[13];
  const void* pbl = d_in[14];
  const void* pg  = d_in[15];
  const void* cwl = d_in[16];
  const void* cbl = d_in[17];
  const void* cg  = d_in[18];

  char* ws = (char*)d_ws;
  ushort* QT      = (ushort*)(ws + 0);         //  512 KB  [2][4096][32] bf16
  ushort* KT      = (ushort*)(ws + 524288);    // 1536 KB  [6][4096][32] bf16
  ushort* Vp      = (ushort*)(ws + 2097152);   // 1024 KB  [2][64][4096] bf16 (sigma')
  float*  S_part  = (float*) (ws + 3145728);   //  384 KB  [4][2*3*4096] f32
  float*  e_part  = (float*) (ws + 3538944);   // 1536 KB  [2][3][16][64][64] f32
  ushort* pam_prt = (ushort*)(ws + 5111808);   // 4096 KB  [2][4][64][4096] bf16
  ushort* Wfull   = (ushort*)(ws + 9306112);   //   32 KB  [2][64][128] bf16
  float*  biasv   = (float*) (ws + 9338880);   //  256 B   [64] f32
  float*  e_red   = (float*) (ws + 9339136);   //   96 KB  [2][3][64][64] f32

  k_prep_all<<< 480, 256, 0, stream>>>(x, y, z, wq, bq, wk1, bk1, wk2, bk2, wk3, bk3,
                                       wv, bv, QT, KT, Vp, e_part);
  k_pass1   <<<1632, 256, 0, stream>>>(QT, KT, e_part, S_part, e_red);
  k_patch   <<<  98, 256, 0, stream>>>(S_part, QT, e_red, x, cwl, cbl, cg, pwl, pbl, pg,
                                       Wfull, biasv);
  k_pam_out <<<1024, 256, 0, stream>>>(QT, KT, Vp, pam_prt);
  k_final   <<< 128, 256, 0, stream>>>(x, pam_prt, Wfull, biasv, d_out);
}